// Round 13
// baseline (365.514 us; speedup 1.0000x reference)
//
#include <hip/hip_runtime.h>

// Problem constants
#define B_   8
#define N_   1024
#define C_   1024
#define H_   16
#define P_   64
#define D_   64
#define MKV  1088      // P_ + N_
#define ROWS 8192      // B_*N_

typedef float f32x4 __attribute__((ext_vector_type(4)));
typedef float f32x16 __attribute__((ext_vector_type(16)));
typedef __bf16 bf16x8 __attribute__((ext_vector_type(8)));
typedef unsigned short u16x8 __attribute__((ext_vector_type(8)));
typedef unsigned short u16x4 __attribute__((ext_vector_type(4)));

__device__ __forceinline__ unsigned short f2bf(float f) {
  unsigned u = __float_as_uint(f);
  u += 0x7fffu + ((u >> 16) & 1u);   // round-to-nearest-even
  return (unsigned short)(u >> 16);
}

// T12 primitive: pack 2 f32 -> 1 dword of 2 bf16 (lo=a, hi=b) in ONE VALU op.
__device__ __forceinline__ unsigned cvt_pk_bf16(float a, float b) {
  unsigned r;
  asm("v_cvt_pk_bf16_f32 %0, %1, %2" : "=v"(r) : "v"(a), "v"(b));
  return r;
}

#define GLDS16(g, l)                                                          \
  __builtin_amdgcn_global_load_lds(                                           \
      (const __attribute__((address_space(1))) void*)(g),                     \
      (__attribute__((address_space(3))) void*)(l), 16, 0, 0)

// ---------------------------------------------------------------------------
// Fused weight-cast (qkv/proj/fc/cproj fp32->bf16) + prefix k/v fill.
__global__ __launch_bounds__(256) void cast_all(
    const float* __restrict__ qkv_w, const float* __restrict__ proj_w,
    const float* __restrict__ fc_w, const float* __restrict__ cproj_w,
    const float* __restrict__ pk, const float* __restrict__ pv,
    unsigned short* __restrict__ qkv_wb, unsigned short* __restrict__ proj_wb,
    unsigned short* __restrict__ fc_wb, unsigned short* __restrict__ cproj_wb,
    unsigned short* __restrict__ Kb, unsigned short* __restrict__ Vb) {
  const int i = blockIdx.x * 256 + threadIdx.x;
  if (i < 1572864) {
    const float* in;
    unsigned short* out;
    int j;
    if (i < 393216)       { in = qkv_w;   out = qkv_wb;   j = i; }
    else if (i < 524288)  { in = proj_w;  out = proj_wb;  j = i - 393216; }
    else if (i < 1048576) { in = fc_w;    out = fc_wb;    j = i - 524288; }
    else                  { in = cproj_w; out = cproj_wb; j = i - 1048576; }
    const float4 a = ((const float4*)in)[j * 2];
    const float4 c = ((const float4*)in)[j * 2 + 1];
    u16x8 o;
    o[0] = f2bf(a.x); o[1] = f2bf(a.y); o[2] = f2bf(a.z); o[3] = f2bf(a.w);
    o[4] = f2bf(c.x); o[5] = f2bf(c.y); o[6] = f2bf(c.z); o[7] = f2bf(c.w);
    *(u16x8*)(out + (size_t)j * 8) = o;
  } else {
    const int i2 = i - 1572864;           // [0, 65536)
    int c8 = i2 & 127, bp = i2 >> 7;
    int b = bp >> 6, p = bp & 63;
    int c = c8 << 3, h = c >> 6, d = c & 63;
    size_t sidx = (size_t)bp * 1024 + c;
    size_t didx = (((size_t)(b * 16 + h)) * MKV + p) * 64 + d;
    float4 a = *(const float4*)(pk + sidx);
    float4 a2 = *(const float4*)(pk + sidx + 4);
    u16x8 o;
    o[0] = f2bf(a.x);  o[1] = f2bf(a.y);  o[2] = f2bf(a.z);  o[3] = f2bf(a.w);
    o[4] = f2bf(a2.x); o[5] = f2bf(a2.y); o[6] = f2bf(a2.z); o[7] = f2bf(a2.w);
    *(u16x8*)(Kb + didx) = o;
    a = *(const float4*)(pv + sidx);
    a2 = *(const float4*)(pv + sidx + 4);
    o[0] = f2bf(a.x);  o[1] = f2bf(a.y);  o[2] = f2bf(a.z);  o[3] = f2bf(a.w);
    o[4] = f2bf(a2.x); o[5] = f2bf(a2.y); o[6] = f2bf(a2.z); o[7] = f2bf(a2.w);
    *(u16x8*)(Vb + didx) = o;
  }
}

// ---------------------------------------------------------------------------
__global__ __launch_bounds__(256) void ln_bf16(
    const float* __restrict__ x, const float* __restrict__ g,
    const float* __restrict__ b, unsigned short* __restrict__ out) {
  const int row = blockIdx.x, t = threadIdx.x;
  const float4 v = ((const float4*)(x + (size_t)row * 1024))[t];
  float s  = v.x + v.y + v.z + v.w;
  float s2 = v.x * v.x + v.y * v.y + v.z * v.z + v.w * v.w;
#pragma unroll
  for (int m = 1; m < 64; m <<= 1) {
    s  += __shfl_xor(s, m);
    s2 += __shfl_xor(s2, m);
  }
  __shared__ float red[8];
  if ((t & 63) == 0) { red[t >> 6] = s; red[4 + (t >> 6)] = s2; }
  __syncthreads();
  s  = red[0] + red[1] + red[2] + red[3];
  s2 = red[4] + red[5] + red[6] + red[7];
  const float mu = s * (1.0f / 1024.0f);
  const float rs = rsqrtf(s2 * (1.0f / 1024.0f) - mu * mu + 1e-5f);
  const float4 gv = ((const float4*)g)[t];
  const float4 bv = ((const float4*)b)[t];
  u16x4 o;
  o[0] = f2bf((v.x - mu) * rs * gv.x + bv.x);
  o[1] = f2bf((v.y - mu) * rs * gv.y + bv.y);
  o[2] = f2bf((v.z - mu) * rs * gv.z + bv.z);
  o[3] = f2bf((v.w - mu) * rs * gv.w + bv.w);
  *(u16x4*)(out + (size_t)row * 1024 + t * 4) = o;
}

// ---------------------------------------------------------------------------
__global__ __launch_bounds__(256) void transpose_v(
    const unsigned short* __restrict__ Vb, unsigned short* __restrict__ Vt) {
  __shared__ __align__(16) unsigned short Ts[64 * 66];
  const int kt = blockIdx.x, bh = blockIdx.y;
  const int t = threadIdx.x;
  const unsigned short* src = Vb + ((size_t)bh * MKV + kt * 64) * 64;
#pragma unroll
  for (int rnd = 0; rnd < 2; rnd++) {
    int chunk = rnd * 256 + t;
    int mr = chunk >> 3, d0 = (chunk & 7) << 3;
    u16x8 a = *(const u16x8*)(src + mr * 64 + d0);
#pragma unroll
    for (int j = 0; j < 8; j += 2)
      *(unsigned*)&Ts[mr * 66 + d0 + j] = (unsigned)a[j] | ((unsigned)a[j + 1] << 16);
  }
  __syncthreads();
#pragma unroll
  for (int rnd = 0; rnd < 2; rnd++) {
    int chunk = rnd * 256 + t;
    int dr = chunk >> 3, m0 = (chunk & 7) << 3;
    u16x8 o;
#pragma unroll
    for (int j = 0; j < 8; j++) o[j] = Ts[(m0 + j) * 66 + dr];
    *(u16x8*)(Vt + ((size_t)bh * 64 + dr) * MKV + kt * 64 + m0) = o;
  }
}

// ---------------------------------------------------------------------------
// GEMM "gemm128" v2: same verified structure (BM=BN=128, BK=64, 4 waves,
// double-buffered 64KB LDS, 2 blocks/CU, one __syncthreads/K-tile, T2 swizzle,
// slab XCD swizzle) but 32x32x16 MFMA (µbench 2382 vs 2075 TF: 8.07 cyc for
// 2x the FLOP of a 4.85-cyc 16x16x32 -> per-tile MFMA 155->128 cyc).
// Per wave: 2x2 tiles of 32x32. A/B frag: row/col = l&31, k = (l>>5)*8+j
// (K-doubling pattern, same as verified 16x16x32). C/D layout HW-verified
// (m74/m101): col = lane&31, row = (reg&3) + 8*(reg>>2) + 4*(lane>>5).
template <int EPI>
__global__ __launch_bounds__(256, 2) void gemm128(
    const unsigned short* __restrict__ A, const unsigned short* __restrict__ Bw,
    const float* __restrict__ bias, const float* __restrict__ resid,
    float* __restrict__ outf, unsigned short* __restrict__ outb,
    unsigned short* __restrict__ qout, unsigned short* __restrict__ kout,
    unsigned short* __restrict__ vout, int Ndim, int Kdim) {
  extern __shared__ __align__(16) char smem[];  // A: 2x16KB @0, B: 2x16KB @32768
  const int t = threadIdx.x;
  const int w = t >> 6, l = t & 63;
  const int wr = w >> 1, wc = w & 1;
  const int l31 = l & 31, hi = l >> 5;
  const int fid = (int)blockIdx.y * 64 + blockIdx.x;
  const int bm = (fid & 7) * 8 + ((fid >> 3) & 7);
  const int bn = fid >> 6;
  const int NS = Kdim >> 6;
  const int sr = t >> 3;
  const int scb = ((t & 7) << 4) ^ ((sr & 7) << 4);
  const size_t rb = (size_t)Kdim * 2;
  const char* Asrc = (const char*)A + (size_t)(bm * 128 + sr) * rb + scb;
  const char* Bsrc = (const char*)Bw + (size_t)(bn * 128 + sr) * rb + scb;
  char* Ad = smem + t * 16;
  char* Bd = smem + 32768 + t * 16;
#define STG(s_, b_) {                                                         \
    const int ko = (s_) << 7;                                                 \
    GLDS16(Asrc + ko,            Ad + (b_) * 16384);                          \
    GLDS16(Asrc + 32 * rb + ko,  Ad + (b_) * 16384 + 4096);                   \
    GLDS16(Asrc + 64 * rb + ko,  Ad + (b_) * 16384 + 8192);                   \
    GLDS16(Asrc + 96 * rb + ko,  Ad + (b_) * 16384 + 12288);                  \
    GLDS16(Bsrc + ko,            Bd + (b_) * 16384);                          \
    GLDS16(Bsrc + 32 * rb + ko,  Bd + (b_) * 16384 + 4096);                   \
    GLDS16(Bsrc + 64 * rb + ko,  Bd + (b_) * 16384 + 8192);                   \
    GLDS16(Bsrc + 96 * rb + ko,  Bd + (b_) * 16384 + 12288); }
  const int rx = (l31 & 7) << 4;          // row-XOR swizzle
  const int g16 = hi << 4;                // k-group byte offset
  const char* arow = smem + (wr * 64 + l31) * 128;
  const char* brow = smem + 32768 + (wc * 64 + l31) * 128;
  f32x16 acc[2][2] = {};
  STG(0, 0);
  __syncthreads();
  for (int s = 0; s < NS; ++s) {
    if (s + 1 < NS) STG(s + 1, (s + 1) & 1);
    const char* ab = arow + (s & 1) * 16384;
    const char* bb = brow + (s & 1) * 16384;
#pragma unroll
    for (int kb = 0; kb < 4; kb++) {
      const int ck = (kb * 32 + g16) ^ rx;
      bf16x8 af0 = *(const bf16x8*)(ab + ck);
      bf16x8 af1 = *(const bf16x8*)(ab + 4096 + ck);
      bf16x8 bv0 = *(const bf16x8*)(bb + ck);
      bf16x8 bv1 = *(const bf16x8*)(bb + 4096 + ck);
      acc[0][0] = __builtin_amdgcn_mfma_f32_32x32x16_bf16(af0, bv0, acc[0][0], 0, 0, 0);
      acc[0][1] = __builtin_amdgcn_mfma_f32_32x32x16_bf16(af0, bv1, acc[0][1], 0, 0, 0);
      acc[1][0] = __builtin_amdgcn_mfma_f32_32x32x16_bf16(af1, bv0, acc[1][0], 0, 0, 0);
      acc[1][1] = __builtin_amdgcn_mfma_f32_32x32x16_bf16(af1, bv1, acc[1][1], 0, 0, 0);
    }
    __syncthreads();
  }
#undef STG
  // ---- epilogue. 32x32 C/D layout (m74/m101): col=l&31,
  // row = (reg&3) + 8*(reg>>2) + 4*hi.
  const int orow0 = bm * 128 + wr * 64 + hi * 4;
  const int ocol0 = bn * 128 + wc * 64 + l31;
  if (EPI == 0) {
    const int which = (bn * 128) >> 10;
#pragma unroll
    for (int mi = 0; mi < 2; mi++)
#pragma unroll
      for (int ni = 0; ni < 2; ni++)
#pragma unroll
        for (int rg = 0; rg < 16; rg++) {
          int m = orow0 + mi * 32 + (rg & 3) + ((rg >> 2) << 3);
          int c = ocol0 + ni * 32;
          int cc = c & 1023;
          int h = cc >> 6, d = cc & 63;
          int b = m >> 10, n = m & 1023;
          float v = acc[mi][ni][rg];
          if (which == 0)   // q scaled by 1/sqrt(D) * log2(e) for exp2 softmax
            qout[(((size_t)(b * 16 + h)) * 1024 + n) * 64 + d] =
                f2bf(v * 0.18033688f);
          else if (which == 1)
            kout[(((size_t)(b * 16 + h)) * MKV + 64 + n) * 64 + d] = f2bf(v);
          else
            vout[(((size_t)(b * 16 + h)) * MKV + 64 + n) * 64 + d] = f2bf(v);
        }
  } else if (EPI == 1) {
#pragma unroll
    for (int mi = 0; mi < 2; mi++)
#pragma unroll
      for (int ni = 0; ni < 2; ni++)
#pragma unroll
        for (int rg = 0; rg < 16; rg++) {
          int m = orow0 + mi * 32 + (rg & 3) + ((rg >> 2) << 3);
          int c = ocol0 + ni * 32;
          size_t idx = (size_t)m * Ndim + c;
          outf[idx] = resid[idx] + acc[mi][ni][rg] + bias[c];
        }
  } else {
#pragma unroll
    for (int mi = 0; mi < 2; mi++)
#pragma unroll
      for (int ni = 0; ni < 2; ni++)
#pragma unroll
        for (int rg = 0; rg < 16; rg++) {
          int m = orow0 + mi * 32 + (rg & 3) + ((rg >> 2) << 3);
          int c = ocol0 + ni * 32;
          size_t idx = (size_t)m * Ndim + c;
          float z = acc[mi][ni][rg] + bias[c];
          outb[idx] = f2bf(z / (1.f + __expf(-1.702f * z)));
        }
  }
}

// ---------------------------------------------------------------------------
// Flash attention v5 (R10-verified): 8-wave, exp2-domain softmax, defer-max,
// cvt_pk bf16 packing, LDS-staged K/V double-buffered, swapped QK^T.
__device__ __forceinline__ bf16x8 pexch(const unsigned pw[4][2], int kk,
                                        int src0, bool lo) {
  const unsigned a0 = pw[2 * kk][0], a1 = pw[2 * kk][1];
  const unsigned b0 = pw[2 * kk + 1][0], b1 = pw[2 * kk + 1][1];
  unsigned wA0 = (unsigned)__shfl((int)a0, src0);
  unsigned wA1 = (unsigned)__shfl((int)a1, src0);
  unsigned wB0 = (unsigned)__shfl((int)b0, src0);
  unsigned wB1 = (unsigned)__shfl((int)b1, src0);
  unsigned wA0h = (unsigned)__shfl((int)a0, src0 + 16);
  unsigned wA1h = (unsigned)__shfl((int)a1, src0 + 16);
  unsigned wB0h = (unsigned)__shfl((int)b0, src0 + 16);
  unsigned wB1h = (unsigned)__shfl((int)b1, src0 + 16);
  union { unsigned u[4]; bf16x8 v; } pf;
  pf.u[0] = lo ? wA0 : wB0;
  pf.u[1] = lo ? wA1 : wB1;
  pf.u[2] = lo ? wA0h : wB0h;
  pf.u[3] = lo ? wA1h : wB1h;
  return pf.v;
}

__global__ __launch_bounds__(512, 4) void flash_attn(
    const unsigned short* __restrict__ Qb, const unsigned short* __restrict__ Kb,
    const unsigned short* __restrict__ Vt, unsigned short* __restrict__ Ob) {
  __shared__ __align__(16) unsigned short KT[2][4096];
  __shared__ __align__(16) unsigned short VT[2][4096];
  const int t = threadIdx.x;
  const int w = t >> 6, l = t & 63;
  const int g = l >> 4, r15 = l & 15;
  const int bh = blockIdx.x, qt = blockIdx.y;
  const unsigned short* Kbh = Kb + (size_t)bh * MKV * 64;
  const unsigned short* Vbh = Vt + (size_t)bh * 64 * MKV;
  const int srow = t >> 3;
  const int scb = ((t & 7) << 4) ^ ((srow & 7) << 4);
  const char* Ksrc0 = (const char*)Kbh + srow * 128 + scb;
  const char* Vsrc0 = (const char*)Vbh + srow * (MKV * 2) + scb;
  const int qbase = qt * 256 + w * 32;
  const unsigned short* Qr0 = Qb + ((size_t)bh * 1024 + qbase + r15) * 64;
  const bf16x8 qf00 = *(const bf16x8*)(Qr0 + g * 8);
  const bf16x8 qf01 = *(const bf16x8*)(Qr0 + 32 + g * 8);
  const bf16x8 qf10 = *(const bf16x8*)(Qr0 + 16 * 64 + g * 8);
  const bf16x8 qf11 = *(const bf16x8*)(Qr0 + 16 * 64 + 32 + g * 8);
  f32x4 Oa0[4] = {}, Oa1[4] = {};
  float m0 = -1e30f, l0 = 0.f, m1 = -1e30f, l1 = 0.f;
  const int src0 = r15 + ((l & 16) << 1);
  const bool lo = (l < 32);
  const int rx = (r15 & 7) << 4;
  GLDS16(Ksrc0, &KT[0][t * 8]);
  GLDS16(Vsrc0, &VT[0][t * 8]);
  __syncthreads();
  int cur = 0;
  for (int kt = 0; kt < 17; ++kt) {
    if (kt < 16) {
      GLDS16(Ksrc0 + (kt + 1) * 8192, &KT[cur ^ 1][t * 8]);
      GLDS16(Vsrc0 + (kt + 1) * 128, &VT[cur ^ 1][t * 8]);
    }
    const char* Kl = (const char*)&KT[cur][0];
    const char* Vl = (const char*)&VT[cur][0];
    f32x4 S0[4], S1[4];
#pragma unroll
    for (int jc = 0; jc < 4; jc++) {
      const char* kr = Kl + jc * 2048 + r15 * 128;
      bf16x8 k0 = *(const bf16x8*)(kr + ((g * 16) ^ rx));
      bf16x8 k1 = *(const bf16x8*)(kr + ((64 + g * 16) ^ rx));
      f32x4 a0 = {}, a1 = {};
      a0 = __builtin_amdgcn_mfma_f32_16x16x32_bf16(k0, qf00, a0, 0, 0, 0);
      a0 = __builtin_amdgcn_mfma_f32_16x16x32_bf16(k1, qf01, a0, 0, 0, 0);
      a1 = __builtin_amdgcn_mfma_f32_16x16x32_bf16(k0, qf10, a1, 0, 0, 0);
      a1 = __builtin_amdgcn_mfma_f32_16x16x32_bf16(k1, qf11, a1, 0, 0, 0);
      S0[jc] = a0; S1[jc] = a1;
    }
    float mx0 = S0[0][0], mx1 = S1[0][0];
#pragma unroll
    for (int jc = 0; jc < 4; jc++)
#pragma unroll
      for (int r = 0; r < 4; r++) {
        mx0 = fmaxf(mx0, S0[jc][r]);
        mx1 = fmaxf(mx1, S1[jc][r]);
      }
    mx0 = fmaxf(mx0, __shfl_xor(mx0, 16));
    mx0 = fmaxf(mx0, __shfl_xor(mx0, 32));
    mx1 = fmaxf(mx1, __shfl_xor(mx1, 16));
    mx1 = fmaxf(mx1, __shfl_xor(mx1, 32));
    if (__any((mx0 > m0 + 8.f) || (mx1 > m1 + 8.f))) {
      float mn0 = fmaxf(m0, mx0);
      float sc0 = exp2f(m0 - mn0);
      m0 = mn0; l0 *= sc0;
      float mn1 = fmaxf(m1, mx1);
      float sc1 = exp2f(m1 - mn1);
      m1 = mn1; l1 *= sc1;
#pragma unroll
      for (int db = 0; db < 4; db++)
#pragma unroll
        for (int r = 0; r < 4; r++) {
          Oa0[db][r] *= sc0;
          Oa1[db][r] *= sc1;
        }
    }
    float rs0 = 0.f, rs1 = 0.f;
#pragma unroll
    for (int jc = 0; jc < 4; jc++)
#pragma unroll
      for (int r = 0; r < 4; r++) {
        float p0 = exp2f(S0[jc][r] - m0);
        float p1 = exp2f(S1[jc][r] - m1);
        S0[jc][r] = p0; S1[jc][r] = p1;
        rs0 += p0; rs1 += p1;
      }
    rs0 += __shfl_xor(rs0, 16);
    rs0 += __shfl_xor(rs0, 32);
    rs1 += __shfl_xor(rs1, 16);
    rs1 += __shfl_xor(rs1, 32);
    l0 += rs0; l1 += rs1;
    unsigned pw0[4][2], pw1[4][2];
#pragma unroll
    for (int jc = 0; jc < 4; jc++) {
      pw0[jc][0] = cvt_pk_bf16(S0[jc][0], S0[jc][1]);
      pw0[jc][1] = cvt_pk_bf16(S0[jc][2], S0[jc][3]);
      pw1[jc][0] = cvt_pk_bf16(S1[jc][0], S1[jc][1]);
      pw1[jc][1] = cvt_pk_bf16(S1[jc][2], S1[jc][3]);
    }
#pragma unroll
    for (int kk = 0; kk < 2; kk++) {
      bf16x8 pf0 = pexch(pw0, kk, src0, lo);
      bf16x8 pf1 = pexch(pw1, kk, src0, lo);
#pragma unroll
      for (int db = 0; db < 4; db++) {
        bf16x8 va = *(const bf16x8*)(Vl + db * 2048 + r15 * 128 +
                                     ((kk * 64 + g * 16) ^ rx));
        Oa0[db] = __builtin_amdgcn_mfma_f32_16x16x32_bf16(va, pf0, Oa0[db], 0, 0, 0);
        Oa1[db] = __builtin_amdgcn_mfma_f32_16x16x32_bf16(va, pf1, Oa1[db], 0, 0, 0);
      }
    }
    __syncthreads();
    cur ^= 1;
  }
  const int b = bh >> 4, h = bh & 15;
  const float i0 = 1.f / l0, i1 = 1.f / l1;
  const int n0 = qbase + r15;
#pragma unroll
  for (int db = 0; db < 4; db++) {
    u16x4 o;
#pragma unroll
    for (int r = 0; r < 4; r++) o[r] = f2bf(Oa0[db][r] * i0);
    *(u16x4*)(Ob + ((size_t)b * 1024 + n0) * 1024 + h * 64 + db * 16 + g * 4) = o;
#pragma unroll
    for (int r = 0; r < 4; r++) o[r] = f2bf(Oa1[db][r] * i1);
    *(u16x4*)(Ob + ((size_t)b * 1024 + n0 + 16) * 1024 + h * 64 + db * 16 + g * 4) = o;
  }
}

// ---------------------------------------------------------------------------
extern "C" void kernel_launch(void* const* d_in, const int* in_sizes, int n_in,
                              void* d_out, int out_size, void* d_ws, size_t ws_size,
                              hipStream_t stream) {
  const float* x       = (const float*)d_in[0];
  const float* pk      = (const float*)d_in[1];
  const float* pv      = (const float*)d_in[2];
  const float* qkv_w   = (const float*)d_in[3];
  const float* proj_w  = (const float*)d_in[4];
  const float* proj_b  = (const float*)d_in[5];
  const float* ln1_g   = (const float*)d_in[6];
  const float* ln1_b   = (const float*)d_in[7];
  const float* ln2_g   = (const float*)d_in[8];
  const float* ln2_b   = (const float*)d_in[9];
  const float* fc_w    = (const float*)d_in[10];
  const float* fc_b    = (const float*)d_in[11];
  const float* cproj_w = (const float*)d_in[12];
  const float* cproj_b = (const float*)d_in[13];
  float* out = (float*)d_out;
  char* ws = (char*)d_ws;

  unsigned short* qkv_wb   = (unsigned short*)(ws + 0);          // 6291456
  unsigned short* proj_wb  = (unsigned short*)(ws + 6291456);    // 2097152
  unsigned short* fc_wb    = (unsigned short*)(ws + 8388608);    // 8388608
  unsigned short* cproj_wb = (unsigned short*)(ws + 16777216);   // 8388608
  float*          x1       = (float*)(ws + 25165824);            // 33554432
  unsigned short* h1       = (unsigned short*)(ws + 58720256);   // 16777216
  unsigned short* o_b      = h1;                                 // alias (h1 dead)
  unsigned short* h2       = (unsigned short*)(ws + 75497472);   // 16777216
  unsigned short* q_buf    = (unsigned short*)(ws + 92274688);   // 16777216
  unsigned short* Kb       = (unsigned short*)(ws + 109051904);  // 17825792
  unsigned short* Vb       = (unsigned short*)(ws + 126877696);  // 17825792
  unsigned short* Vt       = (unsigned short*)(ws + 144703488);  // 17825792
  unsigned short* h3       = (unsigned short*)(ws + 92274688);   // alias (dead)
  if (ws_size < 162529280u) return;

  // allow 64KB dynamic LDS (idempotent host-side calls — capture-safe)
  (void)hipFuncSetAttribute((const void*)gemm128<0>,
      hipFuncAttributeMaxDynamicSharedMemorySize, 65536);
  (void)hipFuncSetAttribute((const void*)gemm128<1>,
      hipFuncAttributeMaxDynamicSharedMemorySize, 65536);
  (void)hipFuncSetAttribute((const void*)gemm128<2>,
      hipFuncAttributeMaxDynamicSharedMemorySize, 65536);

  cast_all<<<6400, 256, 0, stream>>>(qkv_w, proj_w, fc_w, cproj_w, pk, pv,
                                     qkv_wb, proj_wb, fc_wb, cproj_wb, Kb, Vb);
  ln_bf16<<<ROWS, 256, 0, stream>>>(x, ln1_g, ln1_b, h1);
  gemm128<0><<<dim3(64, 24), 256, 65536, stream>>>(
      h1, qkv_wb, nullptr, nullptr, nullptr, nullptr, q_buf, Kb, Vb, 3072, 1024);
  transpose_v<<<dim3(17, 128), 256, 0, stream>>>(Vb, Vt);
  flash_attn<<<dim3(128, 4), 512, 0, stream>>>(q_buf, Kb, Vt, o_b);
  gemm128<1><<<dim3(64, 8), 256, 65536, stream>>>(
      o_b, proj_wb, proj_b, x, x1, nullptr, nullptr, nullptr, nullptr, 1024, 1024);
  ln_bf16<<<ROWS, 256, 0, stream>>>(x1, ln2_g, ln2_b, h2);
  gemm128<2><<<dim3(64, 32), 256, 65536, stream>>>(
      h2, fc_wb, fc_b, nullptr, nullptr, h3, nullptr, nullptr, nullptr, 4096, 1024);
  gemm128<1><<<dim3(64, 8), 256, 65536, stream>>>(
      h3, cproj_wb, cproj_b, x1, out, nullptr, nullptr, nullptr, nullptr, 1024, 4096);
}

// Round 14
// 350.412 us; speedup vs baseline: 1.0431x; 1.0431x over previous
//
#include <hip/hip_runtime.h>

// Problem constants
#define B_   8
#define N_   1024
#define C_   1024
#define H_   16
#define P_   64
#define D_   64
#define MKV  1088      // P_ + N_
#define ROWS 8192      // B_*N_

typedef float f32x4 __attribute__((ext_vector_type(4)));
typedef __bf16 bf16x8 __attribute__((ext_vector_type(8)));
typedef unsigned short u16x8 __attribute__((ext_vector_type(8)));
typedef unsigned short u16x4 __attribute__((ext_vector_type(4)));

__device__ __forceinline__ unsigned short f2bf(float f) {
  unsigned u = __float_as_uint(f);
  u += 0x7fffu + ((u >> 16) & 1u);   // round-to-nearest-even
  return (unsigned short)(u >> 16);
}

// T12 primitive: pack 2 f32 -> 1 dword of 2 bf16 (lo=a, hi=b) in ONE VALU op.
__device__ __forceinline__ unsigned cvt_pk_bf16(float a, float b) {
  unsigned r;
  asm("v_cvt_pk_bf16_f32 %0, %1, %2" : "=v"(r) : "v"(a), "v"(b));
  return r;
}

#define GLDS16(g, l)                                                          \
  __builtin_amdgcn_global_load_lds(                                           \
      (const __attribute__((address_space(1))) void*)(g),                     \
      (__attribute__((address_space(3))) void*)(l), 16, 0, 0)

// ---------------------------------------------------------------------------
// Fused weight-cast (qkv/proj/fc/cproj fp32->bf16) + prefix K/V fill.
// Prefix V goes DIRECTLY into the transposed Vt layout [BH][64][MKV]
// (removes the separate transpose_v kernel entirely).
__global__ __launch_bounds__(256) void cast_all(
    const float* __restrict__ qkv_w, const float* __restrict__ proj_w,
    const float* __restrict__ fc_w, const float* __restrict__ cproj_w,
    const float* __restrict__ pk, const float* __restrict__ pv,
    unsigned short* __restrict__ qkv_wb, unsigned short* __restrict__ proj_wb,
    unsigned short* __restrict__ fc_wb, unsigned short* __restrict__ cproj_wb,
    unsigned short* __restrict__ Kb, unsigned short* __restrict__ Vt) {
  const int i = blockIdx.x * 256 + threadIdx.x;
  if (i < 1572864) {
    const float* in;
    unsigned short* out;
    int j;
    if (i < 393216)       { in = qkv_w;   out = qkv_wb;   j = i; }
    else if (i < 524288)  { in = proj_w;  out = proj_wb;  j = i - 393216; }
    else if (i < 1048576) { in = fc_w;    out = fc_wb;    j = i - 524288; }
    else                  { in = cproj_w; out = cproj_wb; j = i - 1048576; }
    const float4 a = ((const float4*)in)[j * 2];
    const float4 c = ((const float4*)in)[j * 2 + 1];
    u16x8 o;
    o[0] = f2bf(a.x); o[1] = f2bf(a.y); o[2] = f2bf(a.z); o[3] = f2bf(a.w);
    o[4] = f2bf(c.x); o[5] = f2bf(c.y); o[6] = f2bf(c.z); o[7] = f2bf(c.w);
    *(u16x8*)(out + (size_t)j * 8) = o;
  } else {
    const int i2 = i - 1572864;           // [0, 65536)
    int c8 = i2 & 127, bp = i2 >> 7;
    int b = bp >> 6, p = bp & 63;
    int c = c8 << 3, h = c >> 6, d = c & 63;
    size_t sidx = (size_t)bp * 1024 + c;
    const int bh = b * 16 + h;
    // K prefix: row-major [BH][MKV][64]
    size_t didx = ((size_t)bh * MKV + p) * 64 + d;
    float4 a = *(const float4*)(pk + sidx);
    float4 a2 = *(const float4*)(pk + sidx + 4);
    u16x8 o;
    o[0] = f2bf(a.x);  o[1] = f2bf(a.y);  o[2] = f2bf(a.z);  o[3] = f2bf(a.w);
    o[4] = f2bf(a2.x); o[5] = f2bf(a2.y); o[6] = f2bf(a2.z); o[7] = f2bf(a2.w);
    *(u16x8*)(Kb + didx) = o;
    // V prefix: transposed [BH][64][MKV], kv index = p
    a = *(const float4*)(pv + sidx);
    a2 = *(const float4*)(pv + sidx + 4);
    unsigned short vv[8];
    vv[0] = f2bf(a.x);  vv[1] = f2bf(a.y);  vv[2] = f2bf(a.z);  vv[3] = f2bf(a.w);
    vv[4] = f2bf(a2.x); vv[5] = f2bf(a2.y); vv[6] = f2bf(a2.z); vv[7] = f2bf(a2.w);
#pragma unroll
    for (int j = 0; j < 8; j++)
      Vt[((size_t)bh * 64 + d + j) * MKV + p] = vv[j];
  }
}

// ---------------------------------------------------------------------------
__global__ __launch_bounds__(256) void ln_bf16(
    const float* __restrict__ x, const float* __restrict__ g,
    const float* __restrict__ b, unsigned short* __restrict__ out) {
  const int row = blockIdx.x, t = threadIdx.x;
  const float4 v = ((const float4*)(x + (size_t)row * 1024))[t];
  float s  = v.x + v.y + v.z + v.w;
  float s2 = v.x * v.x + v.y * v.y + v.z * v.z + v.w * v.w;
#pragma unroll
  for (int m = 1; m < 64; m <<= 1) {
    s  += __shfl_xor(s, m);
    s2 += __shfl_xor(s2, m);
  }
  __shared__ float red[8];
  if ((t & 63) == 0) { red[t >> 6] = s; red[4 + (t >> 6)] = s2; }
  __syncthreads();
  s  = red[0] + red[1] + red[2] + red[3];
  s2 = red[4] + red[5] + red[6] + red[7];
  const float mu = s * (1.0f / 1024.0f);
  const float rs = rsqrtf(s2 * (1.0f / 1024.0f) - mu * mu + 1e-5f);
  const float4 gv = ((const float4*)g)[t];
  const float4 bv = ((const float4*)b)[t];
  u16x4 o;
  o[0] = f2bf((v.x - mu) * rs * gv.x + bv.x);
  o[1] = f2bf((v.y - mu) * rs * gv.y + bv.y);
  o[2] = f2bf((v.z - mu) * rs * gv.z + bv.z);
  o[3] = f2bf((v.w - mu) * rs * gv.w + bv.w);
  *(u16x4*)(out + (size_t)row * 1024 + t * 4) = o;
}

// ---------------------------------------------------------------------------
// GEMM "gemm128" (R10/R12-verified): BM=BN=128, BK=64, 4 waves, 16x16x32 MFMA,
// double-buffered 64KB LDS -> 2 blocks/CU, ONE __syncthreads per K-tile,
// no manual fences; T2 swizzle both-sides (0 bank conflicts measured);
// slab XCD swizzle. EPI 0 writes q (scaled for exp2 softmax), k row-major,
// and v DIRECTLY TRANSPOSED into Vt [BH][64][MKV] (same scalar-store count
// as the old Vb write; removes transpose_v kernel + 32MB traffic).
template <int EPI>
__global__ __launch_bounds__(256, 2) void gemm128(
    const unsigned short* __restrict__ A, const unsigned short* __restrict__ Bw,
    const float* __restrict__ bias, const float* __restrict__ resid,
    float* __restrict__ outf, unsigned short* __restrict__ outb,
    unsigned short* __restrict__ qout, unsigned short* __restrict__ kout,
    unsigned short* __restrict__ vout, int Ndim, int Kdim) {
  extern __shared__ __align__(16) char smem[];  // A: 2x16KB @0, B: 2x16KB @32768
  const int t = threadIdx.x;
  const int w = t >> 6, l = t & 63;
  const int wr = w >> 1, wc = w & 1;
  const int q4 = l >> 4, r15 = l & 15;
  const int fid = (int)blockIdx.y * 64 + blockIdx.x;
  const int bm = (fid & 7) * 8 + ((fid >> 3) & 7);
  const int bn = fid >> 6;
  const int NS = Kdim >> 6;
  const int sr = t >> 3;
  const int scb = ((t & 7) << 4) ^ ((sr & 7) << 4);
  const size_t rb = (size_t)Kdim * 2;
  const char* Asrc = (const char*)A + (size_t)(bm * 128 + sr) * rb + scb;
  const char* Bsrc = (const char*)Bw + (size_t)(bn * 128 + sr) * rb + scb;
  char* Ad = smem + t * 16;
  char* Bd = smem + 32768 + t * 16;
#define STG(s_, b_) {                                                         \
    const int ko = (s_) << 7;                                                 \
    GLDS16(Asrc + ko,            Ad + (b_) * 16384);                          \
    GLDS16(Asrc + 32 * rb + ko,  Ad + (b_) * 16384 + 4096);                   \
    GLDS16(Asrc + 64 * rb + ko,  Ad + (b_) * 16384 + 8192);                   \
    GLDS16(Asrc + 96 * rb + ko,  Ad + (b_) * 16384 + 12288);                  \
    GLDS16(Bsrc + ko,            Bd + (b_) * 16384);                          \
    GLDS16(Bsrc + 32 * rb + ko,  Bd + (b_) * 16384 + 4096);                   \
    GLDS16(Bsrc + 64 * rb + ko,  Bd + (b_) * 16384 + 8192);                   \
    GLDS16(Bsrc + 96 * rb + ko,  Bd + (b_) * 16384 + 12288); }
  const int rx = (r15 & 7) << 4;
  const int c0 = (q4 << 4) ^ rx;
  const int c1 = c0 ^ 64;
  const char* arow = smem + (wr * 64 + r15) * 128;
  const char* brow = smem + 32768 + (wc * 64 + r15) * 128;
  f32x4 acc[4][4] = {};
  STG(0, 0);
  __syncthreads();
  for (int s = 0; s < NS; ++s) {
    if (s + 1 < NS) STG(s + 1, (s + 1) & 1);
    const char* ab = arow + (s & 1) * 16384;
    const char* bb = brow + (s & 1) * 16384;
#pragma unroll
    for (int kk = 0; kk < 2; kk++) {
      const int ck = kk ? c1 : c0;
      bf16x8 af[4], bv[4];
#pragma unroll
      for (int mf = 0; mf < 4; mf++)
        af[mf] = *(const bf16x8*)(ab + mf * 2048 + ck);
#pragma unroll
      for (int nf = 0; nf < 4; nf++)
        bv[nf] = *(const bf16x8*)(bb + nf * 2048 + ck);
#pragma unroll
      for (int mf = 0; mf < 4; mf++)
#pragma unroll
        for (int nf = 0; nf < 4; nf++)
          acc[mf][nf] = __builtin_amdgcn_mfma_f32_16x16x32_bf16(
              af[mf], bv[nf], acc[mf][nf], 0, 0, 0);
    }
    __syncthreads();
  }
#undef STG
  const int orow0 = bm * 128 + wr * 64 + q4 * 4;
  const int ocol0 = bn * 128 + wc * 64 + r15;
  if (EPI == 0) {
    const int which = (bn * 128) >> 10;
#pragma unroll
    for (int mi = 0; mi < 4; mi++)
#pragma unroll
      for (int ni = 0; ni < 4; ni++)
#pragma unroll
        for (int r = 0; r < 4; r++) {
          int m = orow0 + mi * 16 + r;
          int c = ocol0 + ni * 16;
          int cc = c & 1023;
          int h = cc >> 6, d = cc & 63;
          int b = m >> 10, n = m & 1023;
          float v = acc[mi][ni][r];
          const int bh = b * 16 + h;
          if (which == 0)   // q scaled by 1/sqrt(D) * log2(e) for exp2 softmax
            qout[((size_t)bh * 1024 + n) * 64 + d] = f2bf(v * 0.18033688f);
          else if (which == 1)
            kout[((size_t)bh * MKV + 64 + n) * 64 + d] = f2bf(v);
          else              // v written directly transposed: Vt[bh][d][64+n]
            vout[((size_t)bh * 64 + d) * MKV + 64 + n] = f2bf(v);
        }
  } else if (EPI == 1) {
#pragma unroll
    for (int mi = 0; mi < 4; mi++)
#pragma unroll
      for (int ni = 0; ni < 4; ni++)
#pragma unroll
        for (int r = 0; r < 4; r++) {
          int c = ocol0 + ni * 16;
          size_t idx = (size_t)(orow0 + mi * 16 + r) * Ndim + c;
          outf[idx] = resid[idx] + acc[mi][ni][r] + bias[c];
        }
  } else {
#pragma unroll
    for (int mi = 0; mi < 4; mi++)
#pragma unroll
      for (int ni = 0; ni < 4; ni++)
#pragma unroll
        for (int r = 0; r < 4; r++) {
          int c = ocol0 + ni * 16;
          size_t idx = (size_t)(orow0 + mi * 16 + r) * Ndim + c;
          float z = acc[mi][ni][r] + bias[c];
          outb[idx] = f2bf(z / (1.f + __expf(-1.702f * z)));
        }
  }
}

// ---------------------------------------------------------------------------
// Flash attention v5 (R10-verified): 8-wave, exp2-domain softmax, defer-max,
// cvt_pk bf16 packing, LDS-staged K/V double-buffered, swapped QK^T.
__device__ __forceinline__ bf16x8 pexch(const unsigned pw[4][2], int kk,
                                        int src0, bool lo) {
  const unsigned a0 = pw[2 * kk][0], a1 = pw[2 * kk][1];
  const unsigned b0 = pw[2 * kk + 1][0], b1 = pw[2 * kk + 1][1];
  unsigned wA0 = (unsigned)__shfl((int)a0, src0);
  unsigned wA1 = (unsigned)__shfl((int)a1, src0);
  unsigned wB0 = (unsigned)__shfl((int)b0, src0);
  unsigned wB1 = (unsigned)__shfl((int)b1, src0);
  unsigned wA0h = (unsigned)__shfl((int)a0, src0 + 16);
  unsigned wA1h = (unsigned)__shfl((int)a1, src0 + 16);
  unsigned wB0h = (unsigned)__shfl((int)b0, src0 + 16);
  unsigned wB1h = (unsigned)__shfl((int)b1, src0 + 16);
  union { unsigned u[4]; bf16x8 v; } pf;
  pf.u[0] = lo ? wA0 : wB0;
  pf.u[1] = lo ? wA1 : wB1;
  pf.u[2] = lo ? wA0h : wB0h;
  pf.u[3] = lo ? wA1h : wB1h;
  return pf.v;
}

__global__ __launch_bounds__(512, 4) void flash_attn(
    const unsigned short* __restrict__ Qb, const unsigned short* __restrict__ Kb,
    const unsigned short* __restrict__ Vt, unsigned short* __restrict__ Ob) {
  __shared__ __align__(16) unsigned short KT[2][4096];
  __shared__ __align__(16) unsigned short VT[2][4096];
  const int t = threadIdx.x;
  const int w = t >> 6, l = t & 63;
  const int g = l >> 4, r15 = l & 15;
  const int bh = blockIdx.x, qt = blockIdx.y;
  const unsigned short* Kbh = Kb + (size_t)bh * MKV * 64;
  const unsigned short* Vbh = Vt + (size_t)bh * 64 * MKV;
  const int srow = t >> 3;
  const int scb = ((t & 7) << 4) ^ ((srow & 7) << 4);
  const char* Ksrc0 = (const char*)Kbh + srow * 128 + scb;
  const char* Vsrc0 = (const char*)Vbh + srow * (MKV * 2) + scb;
  const int qbase = qt * 256 + w * 32;
  const unsigned short* Qr0 = Qb + ((size_t)bh * 1024 + qbase + r15) * 64;
  const bf16x8 qf00 = *(const bf16x8*)(Qr0 + g * 8);
  const bf16x8 qf01 = *(const bf16x8*)(Qr0 + 32 + g * 8);
  const bf16x8 qf10 = *(const bf16x8*)(Qr0 + 16 * 64 + g * 8);
  const bf16x8 qf11 = *(const bf16x8*)(Qr0 + 16 * 64 + 32 + g * 8);
  f32x4 Oa0[4] = {}, Oa1[4] = {};
  float m0 = -1e30f, l0 = 0.f, m1 = -1e30f, l1 = 0.f;
  const int src0 = r15 + ((l & 16) << 1);
  const bool lo = (l < 32);
  const int rx = (r15 & 7) << 4;
  GLDS16(Ksrc0, &KT[0][t * 8]);
  GLDS16(Vsrc0, &VT[0][t * 8]);
  __syncthreads();
  int cur = 0;
  for (int kt = 0; kt < 17; ++kt) {
    if (kt < 16) {
      GLDS16(Ksrc0 + (kt + 1) * 8192, &KT[cur ^ 1][t * 8]);
      GLDS16(Vsrc0 + (kt + 1) * 128, &VT[cur ^ 1][t * 8]);
    }
    const char* Kl = (const char*)&KT[cur][0];
    const char* Vl = (const char*)&VT[cur][0];
    f32x4 S0[4], S1[4];
#pragma unroll
    for (int jc = 0; jc < 4; jc++) {
      const char* kr = Kl + jc * 2048 + r15 * 128;
      bf16x8 k0 = *(const bf16x8*)(kr + ((g * 16) ^ rx));
      bf16x8 k1 = *(const bf16x8*)(kr + ((64 + g * 16) ^ rx));
      f32x4 a0 = {}, a1 = {};
      a0 = __builtin_amdgcn_mfma_f32_16x16x32_bf16(k0, qf00, a0, 0, 0, 0);
      a0 = __builtin_amdgcn_mfma_f32_16x16x32_bf16(k1, qf01, a0, 0, 0, 0);
      a1 = __builtin_amdgcn_mfma_f32_16x16x32_bf16(k0, qf10, a1, 0, 0, 0);
      a1 = __builtin_amdgcn_mfma_f32_16x16x32_bf16(k1, qf11, a1, 0, 0, 0);
      S0[jc] = a0; S1[jc] = a1;
    }
    float mx0 = S0[0][0], mx1 = S1[0][0];
#pragma unroll
    for (int jc = 0; jc < 4; jc++)
#pragma unroll
      for (int r = 0; r < 4; r++) {
        mx0 = fmaxf(mx0, S0[jc][r]);
        mx1 = fmaxf(mx1, S1[jc][r]);
      }
    mx0 = fmaxf(mx0, __shfl_xor(mx0, 16));
    mx0 = fmaxf(mx0, __shfl_xor(mx0, 32));
    mx1 = fmaxf(mx1, __shfl_xor(mx1, 16));
    mx1 = fmaxf(mx1, __shfl_xor(mx1, 32));
    if (__any((mx0 > m0 + 8.f) || (mx1 > m1 + 8.f))) {
      float mn0 = fmaxf(m0, mx0);
      float sc0 = exp2f(m0 - mn0);
      m0 = mn0; l0 *= sc0;
      float mn1 = fmaxf(m1, mx1);
      float sc1 = exp2f(m1 - mn1);
      m1 = mn1; l1 *= sc1;
#pragma unroll
      for (int db = 0; db < 4; db++)
#pragma unroll
        for (int r = 0; r < 4; r++) {
          Oa0[db][r] *= sc0;
          Oa1[db][r] *= sc1;
        }
    }
    float rs0 = 0.f, rs1 = 0.f;
#pragma unroll
    for (int jc = 0; jc < 4; jc++)
#pragma unroll
      for (int r = 0; r < 4; r++) {
        float p0 = exp2f(S0[jc][r] - m0);
        float p1 = exp2f(S1[jc][r] - m1);
        S0[jc][r] = p0; S1[jc][r] = p1;
        rs0 += p0; rs1 += p1;
      }
    rs0 += __shfl_xor(rs0, 16);
    rs0 += __shfl_xor(rs0, 32);
    rs1 += __shfl_xor(rs1, 16);
    rs1 += __shfl_xor(rs1, 32);
    l0 += rs0; l1 += rs1;
    unsigned pw0[4][2], pw1[4][2];
#pragma unroll
    for (int jc = 0; jc < 4; jc++) {
      pw0[jc][0] = cvt_pk_bf16(S0[jc][0], S0[jc][1]);
      pw0[jc][1] = cvt_pk_bf16(S0[jc][2], S0[jc][3]);
      pw1[jc][0] = cvt_pk_bf16(S1[jc][0], S1[jc][1]);
      pw1[jc][1] = cvt_pk_bf16(S1[jc][2], S1[jc][3]);
    }
#pragma unroll
    for (int kk = 0; kk < 2; kk++) {
      bf16x8 pf0 = pexch(pw0, kk, src0, lo);
      bf16x8 pf1 = pexch(pw1, kk, src0, lo);
#pragma unroll
      for (int db = 0; db < 4; db++) {
        bf16x8 va = *(const bf16x8*)(Vl + db * 2048 + r15 * 128 +
                                     ((kk * 64 + g * 16) ^ rx));
        Oa0[db] = __builtin_amdgcn_mfma_f32_16x16x32_bf16(va, pf0, Oa0[db], 0, 0, 0);
        Oa1[db] = __builtin_amdgcn_mfma_f32_16x16x32_bf16(va, pf1, Oa1[db], 0, 0, 0);
      }
    }
    __syncthreads();
    cur ^= 1;
  }
  const int b = bh >> 4, h = bh & 15;
  const float i0 = 1.f / l0, i1 = 1.f / l1;
  const int n0 = qbase + r15;
#pragma unroll
  for (int db = 0; db < 4; db++) {
    u16x4 o;
#pragma unroll
    for (int r = 0; r < 4; r++) o[r] = f2bf(Oa0[db][r] * i0);
    *(u16x4*)(Ob + ((size_t)b * 1024 + n0) * 1024 + h * 64 + db * 16 + g * 4) = o;
#pragma unroll
    for (int r = 0; r < 4; r++) o[r] = f2bf(Oa1[db][r] * i1);
    *(u16x4*)(Ob + ((size_t)b * 1024 + n0 + 16) * 1024 + h * 64 + db * 16 + g * 4) = o;
  }
}

// ---------------------------------------------------------------------------
extern "C" void kernel_launch(void* const* d_in, const int* in_sizes, int n_in,
                              void* d_out, int out_size, void* d_ws, size_t ws_size,
                              hipStream_t stream) {
  const float* x       = (const float*)d_in[0];
  const float* pk      = (const float*)d_in[1];
  const float* pv      = (const float*)d_in[2];
  const float* qkv_w   = (const float*)d_in[3];
  const float* proj_w  = (const float*)d_in[4];
  const float* proj_b  = (const float*)d_in[5];
  const float* ln1_g   = (const float*)d_in[6];
  const float* ln1_b   = (const float*)d_in[7];
  const float* ln2_g   = (const float*)d_in[8];
  const float* ln2_b   = (const float*)d_in[9];
  const float* fc_w    = (const float*)d_in[10];
  const float* fc_b    = (const float*)d_in[11];
  const float* cproj_w = (const float*)d_in[12];
  const float* cproj_b = (const float*)d_in[13];
  float* out = (float*)d_out;
  char* ws = (char*)d_ws;

  unsigned short* qkv_wb   = (unsigned short*)(ws + 0);          // 6291456
  unsigned short* proj_wb  = (unsigned short*)(ws + 6291456);    // 2097152
  unsigned short* fc_wb    = (unsigned short*)(ws + 8388608);    // 8388608
  unsigned short* cproj_wb = (unsigned short*)(ws + 16777216);   // 8388608
  float*          x1       = (float*)(ws + 25165824);            // 33554432
  unsigned short* h1       = (unsigned short*)(ws + 58720256);   // 16777216
  unsigned short* o_b      = h1;                                 // alias (h1 dead)
  unsigned short* h2       = (unsigned short*)(ws + 75497472);   // 16777216
  unsigned short* q_buf    = (unsigned short*)(ws + 92274688);   // 16777216
  unsigned short* Kb       = (unsigned short*)(ws + 109051904);  // 17825792
  unsigned short* Vt       = (unsigned short*)(ws + 126877696);  // 17825792
  unsigned short* h3       = (unsigned short*)(ws + 92274688);   // alias (dead)
  if (ws_size < 162529280u) return;

  // allow 64KB dynamic LDS (idempotent host-side calls — capture-safe)
  (void)hipFuncSetAttribute((const void*)gemm128<0>,
      hipFuncAttributeMaxDynamicSharedMemorySize, 65536);
  (void)hipFuncSetAttribute((const void*)gemm128<1>,
      hipFuncAttributeMaxDynamicSharedMemorySize, 65536);
  (void)hipFuncSetAttribute((const void*)gemm128<2>,
      hipFuncAttributeMaxDynamicSharedMemorySize, 65536);

  cast_all<<<6400, 256, 0, stream>>>(qkv_w, proj_w, fc_w, cproj_w, pk, pv,
                                     qkv_wb, proj_wb, fc_wb, cproj_wb, Kb, Vt);
  ln_bf16<<<ROWS, 256, 0, stream>>>(x, ln1_g, ln1_b, h1);
  gemm128<0><<<dim3(64, 24), 256, 65536, stream>>>(
      h1, qkv_wb, nullptr, nullptr, nullptr, nullptr, q_buf, Kb, Vt, 3072, 1024);
  flash_attn<<<dim3(128, 4), 512, 0, stream>>>(q_buf, Kb, Vt, o_b);
  gemm128<1><<<dim3(64, 8), 256, 65536, stream>>>(
      o_b, proj_wb, proj_b, x, x1, nullptr, nullptr, nullptr, nullptr, 1024, 1024);
  ln_bf16<<<ROWS, 256, 0, stream>>>(x1, ln2_g, ln2_b, h2);
  gemm128<2><<<dim3(64, 32), 256, 65536, stream>>>(
      h2, fc_wb, fc_b, nullptr, nullptr, h3, nullptr, nullptr, nullptr, 4096, 1024);
  gemm128<1><<<dim3(64, 8), 256, 65536, stream>>>(
      h3, cproj_wb, cproj_b, x1, out, nullptr, nullptr, nullptr, nullptr, 1024, 4096);
}

// Round 15
// 339.965 us; speedup vs baseline: 1.0752x; 1.0307x over previous
//
#include <hip/hip_runtime.h>

// Problem constants
#define B_   8
#define N_   1024
#define C_   1024
#define H_   16
#define P_   64
#define D_   64
#define MKV  1088      // P_ + N_
#define ROWS 8192      // B_*N_

typedef float f32x4 __attribute__((ext_vector_type(4)));
typedef __bf16 bf16x8 __attribute__((ext_vector_type(8)));
typedef unsigned short u16x8 __attribute__((ext_vector_type(8)));
typedef unsigned short u16x4 __attribute__((ext_vector_type(4)));

__device__ __forceinline__ unsigned short f2bf(float f) {
  unsigned u = __float_as_uint(f);
  u += 0x7fffu + ((u >> 16) & 1u);   // round-to-nearest-even
  return (unsigned short)(u >> 16);
}

// T12 primitive: pack 2 f32 -> 1 dword of 2 bf16 (lo=a, hi=b) in ONE VALU op.
__device__ __forceinline__ unsigned cvt_pk_bf16(float a, float b) {
  unsigned r;
  asm("v_cvt_pk_bf16_f32 %0, %1, %2" : "=v"(r) : "v"(a), "v"(b));
  return r;
}

#define GLDS16(g, l)                                                          \
  __builtin_amdgcn_global_load_lds(                                           \
      (const __attribute__((address_space(1))) void*)(g),                     \
      (__attribute__((address_space(3))) void*)(l), 16, 0, 0)

// ---------------------------------------------------------------------------
// Fused preamble: weight-casts (fp32->bf16), prefix K/V fill (row-major Vb,
// per R14 post-mortem: coalesced stores + separate LDS transpose beats
// scattered transposed stores), AND ln1 (blocks >= 6400 each handle one row).
__global__ __launch_bounds__(256) void cast_all(
    const float* __restrict__ qkv_w, const float* __restrict__ proj_w,
    const float* __restrict__ fc_w, const float* __restrict__ cproj_w,
    const float* __restrict__ pk, const float* __restrict__ pv,
    unsigned short* __restrict__ qkv_wb, unsigned short* __restrict__ proj_wb,
    unsigned short* __restrict__ fc_wb, unsigned short* __restrict__ cproj_wb,
    unsigned short* __restrict__ Kb, unsigned short* __restrict__ Vb,
    const float* __restrict__ x, const float* __restrict__ ln1_g,
    const float* __restrict__ ln1_b, unsigned short* __restrict__ h1) {
  const int blk = blockIdx.x;
  const int t = threadIdx.x;
  if (blk >= 6400) {
    // ---- ln1 segment: one row of x per block
    const int row = blk - 6400;
    const float4 v = ((const float4*)(x + (size_t)row * 1024))[t];
    float s  = v.x + v.y + v.z + v.w;
    float s2 = v.x * v.x + v.y * v.y + v.z * v.z + v.w * v.w;
#pragma unroll
    for (int m = 1; m < 64; m <<= 1) {
      s  += __shfl_xor(s, m);
      s2 += __shfl_xor(s2, m);
    }
    __shared__ float red[8];
    if ((t & 63) == 0) { red[t >> 6] = s; red[4 + (t >> 6)] = s2; }
    __syncthreads();
    s  = red[0] + red[1] + red[2] + red[3];
    s2 = red[4] + red[5] + red[6] + red[7];
    const float mu = s * (1.0f / 1024.0f);
    const float rs = rsqrtf(s2 * (1.0f / 1024.0f) - mu * mu + 1e-5f);
    const float4 gv = ((const float4*)ln1_g)[t];
    const float4 bv = ((const float4*)ln1_b)[t];
    u16x4 o;
    o[0] = f2bf((v.x - mu) * rs * gv.x + bv.x);
    o[1] = f2bf((v.y - mu) * rs * gv.y + bv.y);
    o[2] = f2bf((v.z - mu) * rs * gv.z + bv.z);
    o[3] = f2bf((v.w - mu) * rs * gv.w + bv.w);
    *(u16x4*)(h1 + (size_t)row * 1024 + t * 4) = o;
    return;
  }
  const int i = blk * 256 + t;
  if (i < 1572864) {
    const float* in;
    unsigned short* out;
    int j;
    if (i < 393216)       { in = qkv_w;   out = qkv_wb;   j = i; }
    else if (i < 524288)  { in = proj_w;  out = proj_wb;  j = i - 393216; }
    else if (i < 1048576) { in = fc_w;    out = fc_wb;    j = i - 524288; }
    else                  { in = cproj_w; out = cproj_wb; j = i - 1048576; }
    const float4 a = ((const float4*)in)[j * 2];
    const float4 c = ((const float4*)in)[j * 2 + 1];
    u16x8 o;
    o[0] = f2bf(a.x); o[1] = f2bf(a.y); o[2] = f2bf(a.z); o[3] = f2bf(a.w);
    o[4] = f2bf(c.x); o[5] = f2bf(c.y); o[6] = f2bf(c.z); o[7] = f2bf(c.w);
    *(u16x8*)(out + (size_t)j * 8) = o;
  } else {
    const int i2 = i - 1572864;           // [0, 65536)
    int c8 = i2 & 127, bp = i2 >> 7;
    int b = bp >> 6, p = bp & 63;
    int c = c8 << 3, h = c >> 6, d = c & 63;
    size_t sidx = (size_t)bp * 1024 + c;
    size_t didx = (((size_t)(b * 16 + h)) * MKV + p) * 64 + d;
    float4 a = *(const float4*)(pk + sidx);
    float4 a2 = *(const float4*)(pk + sidx + 4);
    u16x8 o;
    o[0] = f2bf(a.x);  o[1] = f2bf(a.y);  o[2] = f2bf(a.z);  o[3] = f2bf(a.w);
    o[4] = f2bf(a2.x); o[5] = f2bf(a2.y); o[6] = f2bf(a2.z); o[7] = f2bf(a2.w);
    *(u16x8*)(Kb + didx) = o;
    a = *(const float4*)(pv + sidx);
    a2 = *(const float4*)(pv + sidx + 4);
    o[0] = f2bf(a.x);  o[1] = f2bf(a.y);  o[2] = f2bf(a.z);  o[3] = f2bf(a.w);
    o[4] = f2bf(a2.x); o[5] = f2bf(a2.y); o[6] = f2bf(a2.z); o[7] = f2bf(a2.w);
    *(u16x8*)(Vb + didx) = o;
  }
}

// ---------------------------------------------------------------------------
__global__ __launch_bounds__(256) void ln_bf16(
    const float* __restrict__ x, const float* __restrict__ g,
    const float* __restrict__ b, unsigned short* __restrict__ out) {
  const int row = blockIdx.x, t = threadIdx.x;
  const float4 v = ((const float4*)(x + (size_t)row * 1024))[t];
  float s  = v.x + v.y + v.z + v.w;
  float s2 = v.x * v.x + v.y * v.y + v.z * v.z + v.w * v.w;
#pragma unroll
  for (int m = 1; m < 64; m <<= 1) {
    s  += __shfl_xor(s, m);
    s2 += __shfl_xor(s2, m);
  }
  __shared__ float red[8];
  if ((t & 63) == 0) { red[t >> 6] = s; red[4 + (t >> 6)] = s2; }
  __syncthreads();
  s  = red[0] + red[1] + red[2] + red[3];
  s2 = red[4] + red[5] + red[6] + red[7];
  const float mu = s * (1.0f / 1024.0f);
  const float rs = rsqrtf(s2 * (1.0f / 1024.0f) - mu * mu + 1e-5f);
  const float4 gv = ((const float4*)g)[t];
  const float4 bv = ((const float4*)b)[t];
  u16x4 o;
  o[0] = f2bf((v.x - mu) * rs * gv.x + bv.x);
  o[1] = f2bf((v.y - mu) * rs * gv.y + bv.y);
  o[2] = f2bf((v.z - mu) * rs * gv.z + bv.z);
  o[3] = f2bf((v.w - mu) * rs * gv.w + bv.w);
  *(u16x4*)(out + (size_t)row * 1024 + t * 4) = o;
}

// ---------------------------------------------------------------------------
__global__ __launch_bounds__(256) void transpose_v(
    const unsigned short* __restrict__ Vb, unsigned short* __restrict__ Vt) {
  __shared__ __align__(16) unsigned short Ts[64 * 66];
  const int kt = blockIdx.x, bh = blockIdx.y;
  const int t = threadIdx.x;
  const unsigned short* src = Vb + ((size_t)bh * MKV + kt * 64) * 64;
#pragma unroll
  for (int rnd = 0; rnd < 2; rnd++) {
    int chunk = rnd * 256 + t;
    int mr = chunk >> 3, d0 = (chunk & 7) << 3;
    u16x8 a = *(const u16x8*)(src + mr * 64 + d0);
#pragma unroll
    for (int j = 0; j < 8; j += 2)
      *(unsigned*)&Ts[mr * 66 + d0 + j] = (unsigned)a[j] | ((unsigned)a[j + 1] << 16);
  }
  __syncthreads();
#pragma unroll
  for (int rnd = 0; rnd < 2; rnd++) {
    int chunk = rnd * 256 + t;
    int dr = chunk >> 3, m0 = (chunk & 7) << 3;
    u16x8 o;
#pragma unroll
    for (int j = 0; j < 8; j++) o[j] = Ts[(m0 + j) * 66 + dr];
    *(u16x8*)(Vt + ((size_t)bh * 64 + dr) * MKV + kt * 64 + m0) = o;
  }
}

// ---------------------------------------------------------------------------
// GEMM "gemm128" (R10/R12-verified): BM=BN=128, BK=64, 4 waves, 16x16x32 MFMA,
// double-buffered 64KB LDS -> 2 blocks/CU, ONE __syncthreads per K-tile,
// no manual fences; T2 swizzle both-sides (0 bank conflicts); slab XCD swizzle.
template <int EPI>
__global__ __launch_bounds__(256, 2) void gemm128(
    const unsigned short* __restrict__ A, const unsigned short* __restrict__ Bw,
    const float* __restrict__ bias, const float* __restrict__ resid,
    float* __restrict__ outf, unsigned short* __restrict__ outb,
    unsigned short* __restrict__ qout, unsigned short* __restrict__ kout,
    unsigned short* __restrict__ vout, int Ndim, int Kdim) {
  extern __shared__ __align__(16) char smem[];  // A: 2x16KB @0, B: 2x16KB @32768
  const int t = threadIdx.x;
  const int w = t >> 6, l = t & 63;
  const int wr = w >> 1, wc = w & 1;
  const int q4 = l >> 4, r15 = l & 15;
  const int fid = (int)blockIdx.y * 64 + blockIdx.x;
  const int bm = (fid & 7) * 8 + ((fid >> 3) & 7);
  const int bn = fid >> 6;
  const int NS = Kdim >> 6;
  const int sr = t >> 3;
  const int scb = ((t & 7) << 4) ^ ((sr & 7) << 4);
  const size_t rb = (size_t)Kdim * 2;
  const char* Asrc = (const char*)A + (size_t)(bm * 128 + sr) * rb + scb;
  const char* Bsrc = (const char*)Bw + (size_t)(bn * 128 + sr) * rb + scb;
  char* Ad = smem + t * 16;
  char* Bd = smem + 32768 + t * 16;
#define STG(s_, b_) {                                                         \
    const int ko = (s_) << 7;                                                 \
    GLDS16(Asrc + ko,            Ad + (b_) * 16384);                          \
    GLDS16(Asrc + 32 * rb + ko,  Ad + (b_) * 16384 + 4096);                   \
    GLDS16(Asrc + 64 * rb + ko,  Ad + (b_) * 16384 + 8192);                   \
    GLDS16(Asrc + 96 * rb + ko,  Ad + (b_) * 16384 + 12288);                  \
    GLDS16(Bsrc + ko,            Bd + (b_) * 16384);                          \
    GLDS16(Bsrc + 32 * rb + ko,  Bd + (b_) * 16384 + 4096);                   \
    GLDS16(Bsrc + 64 * rb + ko,  Bd + (b_) * 16384 + 8192);                   \
    GLDS16(Bsrc + 96 * rb + ko,  Bd + (b_) * 16384 + 12288); }
  const int rx = (r15 & 7) << 4;
  const int c0 = (q4 << 4) ^ rx;
  const int c1 = c0 ^ 64;
  const char* arow = smem + (wr * 64 + r15) * 128;
  const char* brow = smem + 32768 + (wc * 64 + r15) * 128;
  f32x4 acc[4][4] = {};
  STG(0, 0);
  __syncthreads();
  for (int s = 0; s < NS; ++s) {
    if (s + 1 < NS) STG(s + 1, (s + 1) & 1);
    const char* ab = arow + (s & 1) * 16384;
    const char* bb = brow + (s & 1) * 16384;
#pragma unroll
    for (int kk = 0; kk < 2; kk++) {
      const int ck = kk ? c1 : c0;
      bf16x8 af[4], bv[4];
#pragma unroll
      for (int mf = 0; mf < 4; mf++)
        af[mf] = *(const bf16x8*)(ab + mf * 2048 + ck);
#pragma unroll
      for (int nf = 0; nf < 4; nf++)
        bv[nf] = *(const bf16x8*)(bb + nf * 2048 + ck);
#pragma unroll
      for (int mf = 0; mf < 4; mf++)
#pragma unroll
        for (int nf = 0; nf < 4; nf++)
          acc[mf][nf] = __builtin_amdgcn_mfma_f32_16x16x32_bf16(
              af[mf], bv[nf], acc[mf][nf], 0, 0, 0);
    }
    __syncthreads();
  }
#undef STG
  const int orow0 = bm * 128 + wr * 64 + q4 * 4;
  const int ocol0 = bn * 128 + wc * 64 + r15;
  if (EPI == 0) {
    const int which = (bn * 128) >> 10;
#pragma unroll
    for (int mi = 0; mi < 4; mi++)
#pragma unroll
      for (int ni = 0; ni < 4; ni++)
#pragma unroll
        for (int r = 0; r < 4; r++) {
          int m = orow0 + mi * 16 + r;
          int c = ocol0 + ni * 16;
          int cc = c & 1023;
          int h = cc >> 6, d = cc & 63;
          int b = m >> 10, n = m & 1023;
          float v = acc[mi][ni][r];
          const int bh = b * 16 + h;
          if (which == 0)   // q scaled by 1/sqrt(D) * log2(e) for exp2 softmax
            qout[((size_t)bh * 1024 + n) * 64 + d] = f2bf(v * 0.18033688f);
          else if (which == 1)
            kout[((size_t)bh * MKV + 64 + n) * 64 + d] = f2bf(v);
          else
            vout[((size_t)bh * MKV + 64 + n) * 64 + d] = f2bf(v);
        }
  } else if (EPI == 1) {
#pragma unroll
    for (int mi = 0; mi < 4; mi++)
#pragma unroll
      for (int ni = 0; ni < 4; ni++)
#pragma unroll
        for (int r = 0; r < 4; r++) {
          int c = ocol0 + ni * 16;
          size_t idx = (size_t)(orow0 + mi * 16 + r) * Ndim + c;
          outf[idx] = resid[idx] + acc[mi][ni][r] + bias[c];
        }
  } else {
#pragma unroll
    for (int mi = 0; mi < 4; mi++)
#pragma unroll
      for (int ni = 0; ni < 4; ni++)
#pragma unroll
        for (int r = 0; r < 4; r++) {
          int c = ocol0 + ni * 16;
          size_t idx = (size_t)(orow0 + mi * 16 + r) * Ndim + c;
          float z = acc[mi][ni][r] + bias[c];
          outb[idx] = f2bf(z / (1.f + __expf(-1.702f * z)));
        }
  }
}

// ---------------------------------------------------------------------------
// Flash attention v5 (R10-verified): 8-wave, exp2-domain softmax, defer-max,
// cvt_pk bf16 packing, LDS-staged K/V double-buffered, swapped QK^T.
__device__ __forceinline__ bf16x8 pexch(const unsigned pw[4][2], int kk,
                                        int src0, bool lo) {
  const unsigned a0 = pw[2 * kk][0], a1 = pw[2 * kk][1];
  const unsigned b0 = pw[2 * kk + 1][0], b1 = pw[2 * kk + 1][1];
  unsigned wA0 = (unsigned)__shfl((int)a0, src0);
  unsigned wA1 = (unsigned)__shfl((int)a1, src0);
  unsigned wB0 = (unsigned)__shfl((int)b0, src0);
  unsigned wB1 = (unsigned)__shfl((int)b1, src0);
  unsigned wA0h = (unsigned)__shfl((int)a0, src0 + 16);
  unsigned wA1h = (unsigned)__shfl((int)a1, src0 + 16);
  unsigned wB0h = (unsigned)__shfl((int)b0, src0 + 16);
  unsigned wB1h = (unsigned)__shfl((int)b1, src0 + 16);
  union { unsigned u[4]; bf16x8 v; } pf;
  pf.u[0] = lo ? wA0 : wB0;
  pf.u[1] = lo ? wA1 : wB1;
  pf.u[2] = lo ? wA0h : wB0h;
  pf.u[3] = lo ? wA1h : wB1h;
  return pf.v;
}

__global__ __launch_bounds__(512, 4) void flash_attn(
    const unsigned short* __restrict__ Qb, const unsigned short* __restrict__ Kb,
    const unsigned short* __restrict__ Vt, unsigned short* __restrict__ Ob) {
  __shared__ __align__(16) unsigned short KT[2][4096];
  __shared__ __align__(16) unsigned short VT[2][4096];
  const int t = threadIdx.x;
  const int w = t >> 6, l = t & 63;
  const int g = l >> 4, r15 = l & 15;
  const int bh = blockIdx.x, qt = blockIdx.y;
  const unsigned short* Kbh = Kb + (size_t)bh * MKV * 64;
  const unsigned short* Vbh = Vt + (size_t)bh * 64 * MKV;
  const int srow = t >> 3;
  const int scb = ((t & 7) << 4) ^ ((srow & 7) << 4);
  const char* Ksrc0 = (const char*)Kbh + srow * 128 + scb;
  const char* Vsrc0 = (const char*)Vbh + srow * (MKV * 2) + scb;
  const int qbase = qt * 256 + w * 32;
  const unsigned short* Qr0 = Qb + ((size_t)bh * 1024 + qbase + r15) * 64;
  const bf16x8 qf00 = *(const bf16x8*)(Qr0 + g * 8);
  const bf16x8 qf01 = *(const bf16x8*)(Qr0 + 32 + g * 8);
  const bf16x8 qf10 = *(const bf16x8*)(Qr0 + 16 * 64 + g * 8);
  const bf16x8 qf11 = *(const bf16x8*)(Qr0 + 16 * 64 + 32 + g * 8);
  f32x4 Oa0[4] = {}, Oa1[4] = {};
  float m0 = -1e30f, l0 = 0.f, m1 = -1e30f, l1 = 0.f;
  const int src0 = r15 + ((l & 16) << 1);
  const bool lo = (l < 32);
  const int rx = (r15 & 7) << 4;
  GLDS16(Ksrc0, &KT[0][t * 8]);
  GLDS16(Vsrc0, &VT[0][t * 8]);
  __syncthreads();
  int cur = 0;
  for (int kt = 0; kt < 17; ++kt) {
    if (kt < 16) {
      GLDS16(Ksrc0 + (kt + 1) * 8192, &KT[cur ^ 1][t * 8]);
      GLDS16(Vsrc0 + (kt + 1) * 128, &VT[cur ^ 1][t * 8]);
    }
    const char* Kl = (const char*)&KT[cur][0];
    const char* Vl = (const char*)&VT[cur][0];
    f32x4 S0[4], S1[4];
#pragma unroll
    for (int jc = 0; jc < 4; jc++) {
      const char* kr = Kl + jc * 2048 + r15 * 128;
      bf16x8 k0 = *(const bf16x8*)(kr + ((g * 16) ^ rx));
      bf16x8 k1 = *(const bf16x8*)(kr + ((64 + g * 16) ^ rx));
      f32x4 a0 = {}, a1 = {};
      a0 = __builtin_amdgcn_mfma_f32_16x16x32_bf16(k0, qf00, a0, 0, 0, 0);
      a0 = __builtin_amdgcn_mfma_f32_16x16x32_bf16(k1, qf01, a0, 0, 0, 0);
      a1 = __builtin_amdgcn_mfma_f32_16x16x32_bf16(k0, qf10, a1, 0, 0, 0);
      a1 = __builtin_amdgcn_mfma_f32_16x16x32_bf16(k1, qf11, a1, 0, 0, 0);
      S0[jc] = a0; S1[jc] = a1;
    }
    float mx0 = S0[0][0], mx1 = S1[0][0];
#pragma unroll
    for (int jc = 0; jc < 4; jc++)
#pragma unroll
      for (int r = 0; r < 4; r++) {
        mx0 = fmaxf(mx0, S0[jc][r]);
        mx1 = fmaxf(mx1, S1[jc][r]);
      }
    mx0 = fmaxf(mx0, __shfl_xor(mx0, 16));
    mx0 = fmaxf(mx0, __shfl_xor(mx0, 32));
    mx1 = fmaxf(mx1, __shfl_xor(mx1, 16));
    mx1 = fmaxf(mx1, __shfl_xor(mx1, 32));
    if (__any((mx0 > m0 + 8.f) || (mx1 > m1 + 8.f))) {
      float mn0 = fmaxf(m0, mx0);
      float sc0 = exp2f(m0 - mn0);
      m0 = mn0; l0 *= sc0;
      float mn1 = fmaxf(m1, mx1);
      float sc1 = exp2f(m1 - mn1);
      m1 = mn1; l1 *= sc1;
#pragma unroll
      for (int db = 0; db < 4; db++)
#pragma unroll
        for (int r = 0; r < 4; r++) {
          Oa0[db][r] *= sc0;
          Oa1[db][r] *= sc1;
        }
    }
    float rs0 = 0.f, rs1 = 0.f;
#pragma unroll
    for (int jc = 0; jc < 4; jc++)
#pragma unroll
      for (int r = 0; r < 4; r++) {
        float p0 = exp2f(S0[jc][r] - m0);
        float p1 = exp2f(S1[jc][r] - m1);
        S0[jc][r] = p0; S1[jc][r] = p1;
        rs0 += p0; rs1 += p1;
      }
    rs0 += __shfl_xor(rs0, 16);
    rs0 += __shfl_xor(rs0, 32);
    rs1 += __shfl_xor(rs1, 16);
    rs1 += __shfl_xor(rs1, 32);
    l0 += rs0; l1 += rs1;
    unsigned pw0[4][2], pw1[4][2];
#pragma unroll
    for (int jc = 0; jc < 4; jc++) {
      pw0[jc][0] = cvt_pk_bf16(S0[jc][0], S0[jc][1]);
      pw0[jc][1] = cvt_pk_bf16(S0[jc][2], S0[jc][3]);
      pw1[jc][0] = cvt_pk_bf16(S1[jc][0], S1[jc][1]);
      pw1[jc][1] = cvt_pk_bf16(S1[jc][2], S1[jc][3]);
    }
#pragma unroll
    for (int kk = 0; kk < 2; kk++) {
      bf16x8 pf0 = pexch(pw0, kk, src0, lo);
      bf16x8 pf1 = pexch(pw1, kk, src0, lo);
#pragma unroll
      for (int db = 0; db < 4; db++) {
        bf16x8 va = *(const bf16x8*)(Vl + db * 2048 + r15 * 128 +
                                     ((kk * 64 + g * 16) ^ rx));
        Oa0[db] = __builtin_amdgcn_mfma_f32_16x16x32_bf16(va, pf0, Oa0[db], 0, 0, 0);
        Oa1[db] = __builtin_amdgcn_mfma_f32_16x16x32_bf16(va, pf1, Oa1[db], 0, 0, 0);
      }
    }
    __syncthreads();
    cur ^= 1;
  }
  const int b = bh >> 4, h = bh & 15;
  const float i0 = 1.f / l0, i1 = 1.f / l1;
  const int n0 = qbase + r15;
#pragma unroll
  for (int db = 0; db < 4; db++) {
    u16x4 o;
#pragma unroll
    for (int r = 0; r < 4; r++) o[r] = f2bf(Oa0[db][r] * i0);
    *(u16x4*)(Ob + ((size_t)b * 1024 + n0) * 1024 + h * 64 + db * 16 + g * 4) = o;
#pragma unroll
    for (int r = 0; r < 4; r++) o[r] = f2bf(Oa1[db][r] * i1);
    *(u16x4*)(Ob + ((size_t)b * 1024 + n0 + 16) * 1024 + h * 64 + db * 16 + g * 4) = o;
  }
}

// ---------------------------------------------------------------------------
extern "C" void kernel_launch(void* const* d_in, const int* in_sizes, int n_in,
                              void* d_out, int out_size, void* d_ws, size_t ws_size,
                              hipStream_t stream) {
  const float* x       = (const float*)d_in[0];
  const float* pk      = (const float*)d_in[1];
  const float* pv      = (const float*)d_in[2];
  const float* qkv_w   = (const float*)d_in[3];
  const float* proj_w  = (const float*)d_in[4];
  const float* proj_b  = (const float*)d_in[5];
  const float* ln1_g   = (const float*)d_in[6];
  const float* ln1_b   = (const float*)d_in[7];
  const float* ln2_g   = (const float*)d_in[8];
  const float* ln2_b   = (const float*)d_in[9];
  const float* fc_w    = (const float*)d_in[10];
  const float* fc_b    = (const float*)d_in[11];
  const float* cproj_w = (const float*)d_in[12];
  const float* cproj_b = (const float*)d_in[13];
  float* out = (float*)d_out;
  char* ws = (char*)d_ws;

  unsigned short* qkv_wb   = (unsigned short*)(ws + 0);          // 6291456
  unsigned short* proj_wb  = (unsigned short*)(ws + 6291456);    // 2097152
  unsigned short* fc_wb    = (unsigned short*)(ws + 8388608);    // 8388608
  unsigned short* cproj_wb = (unsigned short*)(ws + 16777216);   // 8388608
  float*          x1       = (float*)(ws + 25165824);            // 33554432
  unsigned short* h1       = (unsigned short*)(ws + 58720256);   // 16777216
  unsigned short* o_b      = h1;                                 // alias (h1 dead)
  unsigned short* h2       = (unsigned short*)(ws + 75497472);   // 16777216
  unsigned short* q_buf    = (unsigned short*)(ws + 92274688);   // 16777216
  unsigned short* Kb       = (unsigned short*)(ws + 109051904);  // 17825792
  unsigned short* Vb       = (unsigned short*)(ws + 126877696);  // 17825792
  unsigned short* Vt       = (unsigned short*)(ws + 144703488);  // 17825792
  unsigned short* h3       = (unsigned short*)(ws + 92274688);   // alias (dead)
  if (ws_size < 162529280u) return;

  // allow 64KB dynamic LDS (idempotent host-side calls — capture-safe)
  (void)hipFuncSetAttribute((const void*)gemm128<0>,
      hipFuncAttributeMaxDynamicSharedMemorySize, 65536);
  (void)hipFuncSetAttribute((const void*)gemm128<1>,
      hipFuncAttributeMaxDynamicSharedMemorySize, 65536);
  (void)hipFuncSetAttribute((const void*)gemm128<2>,
      hipFuncAttributeMaxDynamicSharedMemorySize, 65536);

  cast_all<<<6400 + ROWS, 256, 0, stream>>>(
      qkv_w, proj_w, fc_w, cproj_w, pk, pv,
      qkv_wb, proj_wb, fc_wb, cproj_wb, Kb, Vb, x, ln1_g, ln1_b, h1);
  gemm128<0><<<dim3(64, 24), 256, 65536, stream>>>(
      h1, qkv_wb, nullptr, nullptr, nullptr, nullptr, q_buf, Kb, Vb, 3072, 1024);
  transpose_v<<<dim3(17, 128), 256, 0, stream>>>(Vb, Vt);
  flash_attn<<<dim3(128, 4), 512, 0, stream>>>(q_buf, Kb, Vt, o_b);
  gemm128<1><<<dim3(64, 8), 256, 65536, stream>>>(
      o_b, proj_wb, proj_b, x, x1, nullptr, nullptr, nullptr, nullptr, 1024, 1024);
  ln_bf16<<<ROWS, 256, 0, stream>>>(x1, ln2_g, ln2_b, h2);
  gemm128<2><<<dim3(64, 32), 256, 65536, stream>>>(
      h2, fc_wb, fc_b, nullptr, nullptr, h3, nullptr, nullptr, nullptr, 4096, 1024);
  gemm128<1><<<dim3(64, 8), 256, 65536, stream>>>(
      h3, cproj_wb, cproj_b, x1, out, nullptr, nullptr, nullptr, nullptr, 1024, 4096);
}

// Round 16
// 334.624 us; speedup vs baseline: 1.0923x; 1.0160x over previous
//
#include <hip/hip_runtime.h>

// Problem constants
#define B_   8
#define N_   1024
#define C_   1024
#define H_   16
#define P_   64
#define D_   64
#define MKV  1088      // P_ + N_
#define ROWS 8192      // B_*N_

typedef float f32x4 __attribute__((ext_vector_type(4)));
typedef __bf16 bf16x8 __attribute__((ext_vector_type(8)));
typedef unsigned short u16x8 __attribute__((ext_vector_type(8)));
typedef unsigned short u16x4 __attribute__((ext_vector_type(4)));

__device__ __forceinline__ unsigned short f2bf(float f) {
  unsigned u = __float_as_uint(f);
  u += 0x7fffu + ((u >> 16) & 1u);   // round-to-nearest-even
  return (unsigned short)(u >> 16);
}
__device__ __forceinline__ float bf2f(unsigned short u) {
  return __uint_as_float((unsigned)u << 16);
}

// T12 primitive: pack 2 f32 -> 1 dword of 2 bf16 (lo=a, hi=b) in ONE VALU op.
__device__ __forceinline__ unsigned cvt_pk_bf16(float a, float b) {
  unsigned r;
  asm("v_cvt_pk_bf16_f32 %0, %1, %2" : "=v"(r) : "v"(a), "v"(b));
  return r;
}

#define GLDS16(g, l)                                                          \
  __builtin_amdgcn_global_load_lds(                                           \
      (const __attribute__((address_space(1))) void*)(g),                     \
      (__attribute__((address_space(3))) void*)(l), 16, 0, 0)

// ---------------------------------------------------------------------------
// Fused preamble: weight-casts (fp32->bf16), prefix K/V fill, AND ln1.
__global__ __launch_bounds__(256) void cast_all(
    const float* __restrict__ qkv_w, const float* __restrict__ proj_w,
    const float* __restrict__ fc_w, const float* __restrict__ cproj_w,
    const float* __restrict__ pk, const float* __restrict__ pv,
    unsigned short* __restrict__ qkv_wb, unsigned short* __restrict__ proj_wb,
    unsigned short* __restrict__ fc_wb, unsigned short* __restrict__ cproj_wb,
    unsigned short* __restrict__ Kb, unsigned short* __restrict__ Vb,
    const float* __restrict__ x, const float* __restrict__ ln1_g,
    const float* __restrict__ ln1_b, unsigned short* __restrict__ h1) {
  const int blk = blockIdx.x;
  const int t = threadIdx.x;
  if (blk >= 6400) {
    // ---- ln1 segment: one row of x per block
    const int row = blk - 6400;
    const float4 v = ((const float4*)(x + (size_t)row * 1024))[t];
    float s  = v.x + v.y + v.z + v.w;
    float s2 = v.x * v.x + v.y * v.y + v.z * v.z + v.w * v.w;
#pragma unroll
    for (int m = 1; m < 64; m <<= 1) {
      s  += __shfl_xor(s, m);
      s2 += __shfl_xor(s2, m);
    }
    __shared__ float red[8];
    if ((t & 63) == 0) { red[t >> 6] = s; red[4 + (t >> 6)] = s2; }
    __syncthreads();
    s  = red[0] + red[1] + red[2] + red[3];
    s2 = red[4] + red[5] + red[6] + red[7];
    const float mu = s * (1.0f / 1024.0f);
    const float rs = rsqrtf(s2 * (1.0f / 1024.0f) - mu * mu + 1e-5f);
    const float4 gv = ((const float4*)ln1_g)[t];
    const float4 bv = ((const float4*)ln1_b)[t];
    u16x4 o;
    o[0] = f2bf((v.x - mu) * rs * gv.x + bv.x);
    o[1] = f2bf((v.y - mu) * rs * gv.y + bv.y);
    o[2] = f2bf((v.z - mu) * rs * gv.z + bv.z);
    o[3] = f2bf((v.w - mu) * rs * gv.w + bv.w);
    *(u16x4*)(h1 + (size_t)row * 1024 + t * 4) = o;
    return;
  }
  const int i = blk * 256 + t;
  if (i < 1572864) {
    const float* in;
    unsigned short* out;
    int j;
    if (i < 393216)       { in = qkv_w;   out = qkv_wb;   j = i; }
    else if (i < 524288)  { in = proj_w;  out = proj_wb;  j = i - 393216; }
    else if (i < 1048576) { in = fc_w;    out = fc_wb;    j = i - 524288; }
    else                  { in = cproj_w; out = cproj_wb; j = i - 1048576; }
    const float4 a = ((const float4*)in)[j * 2];
    const float4 c = ((const float4*)in)[j * 2 + 1];
    u16x8 o;
    o[0] = f2bf(a.x); o[1] = f2bf(a.y); o[2] = f2bf(a.z); o[3] = f2bf(a.w);
    o[4] = f2bf(c.x); o[5] = f2bf(c.y); o[6] = f2bf(c.z); o[7] = f2bf(c.w);
    *(u16x8*)(out + (size_t)j * 8) = o;
  } else {
    const int i2 = i - 1572864;           // [0, 65536)
    int c8 = i2 & 127, bp = i2 >> 7;
    int b = bp >> 6, p = bp & 63;
    int c = c8 << 3, h = c >> 6, d = c & 63;
    size_t sidx = (size_t)bp * 1024 + c;
    size_t didx = (((size_t)(b * 16 + h)) * MKV + p) * 64 + d;
    float4 a = *(const float4*)(pk + sidx);
    float4 a2 = *(const float4*)(pk + sidx + 4);
    u16x8 o;
    o[0] = f2bf(a.x);  o[1] = f2bf(a.y);  o[2] = f2bf(a.z);  o[3] = f2bf(a.w);
    o[4] = f2bf(a2.x); o[5] = f2bf(a2.y); o[6] = f2bf(a2.z); o[7] = f2bf(a2.w);
    *(u16x8*)(Kb + didx) = o;
    a = *(const float4*)(pv + sidx);
    a2 = *(const float4*)(pv + sidx + 4);
    o[0] = f2bf(a.x);  o[1] = f2bf(a.y);  o[2] = f2bf(a.z);  o[3] = f2bf(a.w);
    o[4] = f2bf(a2.x); o[5] = f2bf(a2.y); o[6] = f2bf(a2.z); o[7] = f2bf(a2.w);
    *(u16x8*)(Vb + didx) = o;
  }
}

// ---------------------------------------------------------------------------
// LayerNorm over a bf16 row (for the bf16 residual stream x1b).
__global__ __launch_bounds__(256) void ln_bf16b(
    const unsigned short* __restrict__ xb, const float* __restrict__ g,
    const float* __restrict__ b, unsigned short* __restrict__ out) {
  const int row = blockIdx.x, t = threadIdx.x;
  const u16x4 vb = ((const u16x4*)(xb + (size_t)row * 1024))[t];
  float v0 = bf2f(vb[0]), v1 = bf2f(vb[1]), v2 = bf2f(vb[2]), v3 = bf2f(vb[3]);
  float s  = v0 + v1 + v2 + v3;
  float s2 = v0 * v0 + v1 * v1 + v2 * v2 + v3 * v3;
#pragma unroll
  for (int m = 1; m < 64; m <<= 1) {
    s  += __shfl_xor(s, m);
    s2 += __shfl_xor(s2, m);
  }
  __shared__ float red[8];
  if ((t & 63) == 0) { red[t >> 6] = s; red[4 + (t >> 6)] = s2; }
  __syncthreads();
  s  = red[0] + red[1] + red[2] + red[3];
  s2 = red[4] + red[5] + red[6] + red[7];
  const float mu = s * (1.0f / 1024.0f);
  const float rs = rsqrtf(s2 * (1.0f / 1024.0f) - mu * mu + 1e-5f);
  const float4 gv = ((const float4*)g)[t];
  const float4 bv = ((const float4*)b)[t];
  u16x4 o;
  o[0] = f2bf((v0 - mu) * rs * gv.x + bv.x);
  o[1] = f2bf((v1 - mu) * rs * gv.y + bv.y);
  o[2] = f2bf((v2 - mu) * rs * gv.z + bv.z);
  o[3] = f2bf((v3 - mu) * rs * gv.w + bv.w);
  *(u16x4*)(out + (size_t)row * 1024 + t * 4) = o;
}

// ---------------------------------------------------------------------------
__global__ __launch_bounds__(256) void transpose_v(
    const unsigned short* __restrict__ Vb, unsigned short* __restrict__ Vt) {
  __shared__ __align__(16) unsigned short Ts[64 * 66];
  const int kt = blockIdx.x, bh = blockIdx.y;
  const int t = threadIdx.x;
  const unsigned short* src = Vb + ((size_t)bh * MKV + kt * 64) * 64;
#pragma unroll
  for (int rnd = 0; rnd < 2; rnd++) {
    int chunk = rnd * 256 + t;
    int mr = chunk >> 3, d0 = (chunk & 7) << 3;
    u16x8 a = *(const u16x8*)(src + mr * 64 + d0);
#pragma unroll
    for (int j = 0; j < 8; j += 2)
      *(unsigned*)&Ts[mr * 66 + d0 + j] = (unsigned)a[j] | ((unsigned)a[j + 1] << 16);
  }
  __syncthreads();
#pragma unroll
  for (int rnd = 0; rnd < 2; rnd++) {
    int chunk = rnd * 256 + t;
    int dr = chunk >> 3, m0 = (chunk & 7) << 3;
    u16x8 o;
#pragma unroll
    for (int j = 0; j < 8; j++) o[j] = Ts[(m0 + j) * 66 + dr];
    *(u16x8*)(Vt + ((size_t)bh * 64 + dr) * MKV + kt * 64 + m0) = o;
  }
}

// ---------------------------------------------------------------------------
// GEMM "gemm128" (R10/R12/R15-verified core): BM=BN=128, BK=64, 4 waves,
// 16x16x32 MFMA, double-buffered 64KB LDS, 2 blocks/CU, one barrier/K-tile,
// T2 swizzle both-sides (0 conflicts), slab XCD swizzle.
// EPI 0: qkv scatter. EPI 2: quickgelu bf16.
// EPI 3: proj -> x1b = bf16(x_f32 + acc + bias)     (bf16 residual stream)
// EPI 4: cproj -> out_f32 = f32(x1b) + acc + bias
template <int EPI>
__global__ __launch_bounds__(256, 2) void gemm128(
    const unsigned short* __restrict__ A, const unsigned short* __restrict__ Bw,
    const float* __restrict__ bias, const float* __restrict__ resid,
    const unsigned short* __restrict__ residb,
    float* __restrict__ outf, unsigned short* __restrict__ outb,
    unsigned short* __restrict__ qout, unsigned short* __restrict__ kout,
    unsigned short* __restrict__ vout, int Ndim, int Kdim) {
  extern __shared__ __align__(16) char smem[];  // A: 2x16KB @0, B: 2x16KB @32768
  const int t = threadIdx.x;
  const int w = t >> 6, l = t & 63;
  const int wr = w >> 1, wc = w & 1;
  const int q4 = l >> 4, r15 = l & 15;
  const int fid = (int)blockIdx.y * 64 + blockIdx.x;
  const int bm = (fid & 7) * 8 + ((fid >> 3) & 7);
  const int bn = fid >> 6;
  const int NS = Kdim >> 6;
  const int sr = t >> 3;
  const int scb = ((t & 7) << 4) ^ ((sr & 7) << 4);
  const size_t rb = (size_t)Kdim * 2;
  const char* Asrc = (const char*)A + (size_t)(bm * 128 + sr) * rb + scb;
  const char* Bsrc = (const char*)Bw + (size_t)(bn * 128 + sr) * rb + scb;
  char* Ad = smem + t * 16;
  char* Bd = smem + 32768 + t * 16;
#define STG(s_, b_) {                                                         \
    const int ko = (s_) << 7;                                                 \
    GLDS16(Asrc + ko,            Ad + (b_) * 16384);                          \
    GLDS16(Asrc + 32 * rb + ko,  Ad + (b_) * 16384 + 4096);                   \
    GLDS16(Asrc + 64 * rb + ko,  Ad + (b_) * 16384 + 8192);                   \
    GLDS16(Asrc + 96 * rb + ko,  Ad + (b_) * 16384 + 12288);                  \
    GLDS16(Bsrc + ko,            Bd + (b_) * 16384);                          \
    GLDS16(Bsrc + 32 * rb + ko,  Bd + (b_) * 16384 + 4096);                   \
    GLDS16(Bsrc + 64 * rb + ko,  Bd + (b_) * 16384 + 8192);                   \
    GLDS16(Bsrc + 96 * rb + ko,  Bd + (b_) * 16384 + 12288); }
  const int rx = (r15 & 7) << 4;
  const int c0 = (q4 << 4) ^ rx;
  const int c1 = c0 ^ 64;
  const char* arow = smem + (wr * 64 + r15) * 128;
  const char* brow = smem + 32768 + (wc * 64 + r15) * 128;
  f32x4 acc[4][4] = {};
  STG(0, 0);
  __syncthreads();
  for (int s = 0; s < NS; ++s) {
    if (s + 1 < NS) STG(s + 1, (s + 1) & 1);
    const char* ab = arow + (s & 1) * 16384;
    const char* bb = brow + (s & 1) * 16384;
#pragma unroll
    for (int kk = 0; kk < 2; kk++) {
      const int ck = kk ? c1 : c0;
      bf16x8 af[4], bv[4];
#pragma unroll
      for (int mf = 0; mf < 4; mf++)
        af[mf] = *(const bf16x8*)(ab + mf * 2048 + ck);
#pragma unroll
      for (int nf = 0; nf < 4; nf++)
        bv[nf] = *(const bf16x8*)(bb + nf * 2048 + ck);
#pragma unroll
      for (int mf = 0; mf < 4; mf++)
#pragma unroll
        for (int nf = 0; nf < 4; nf++)
          acc[mf][nf] = __builtin_amdgcn_mfma_f32_16x16x32_bf16(
              af[mf], bv[nf], acc[mf][nf], 0, 0, 0);
    }
    __syncthreads();
  }
#undef STG
  const int orow0 = bm * 128 + wr * 64 + q4 * 4;
  const int ocol0 = bn * 128 + wc * 64 + r15;
  if (EPI == 0) {
    const int which = (bn * 128) >> 10;
#pragma unroll
    for (int mi = 0; mi < 4; mi++)
#pragma unroll
      for (int ni = 0; ni < 4; ni++)
#pragma unroll
        for (int r = 0; r < 4; r++) {
          int m = orow0 + mi * 16 + r;
          int c = ocol0 + ni * 16;
          int cc = c & 1023;
          int h = cc >> 6, d = cc & 63;
          int b = m >> 10, n = m & 1023;
          float v = acc[mi][ni][r];
          const int bh = b * 16 + h;
          if (which == 0)   // q scaled by 1/sqrt(D) * log2(e) for exp2 softmax
            qout[((size_t)bh * 1024 + n) * 64 + d] = f2bf(v * 0.18033688f);
          else if (which == 1)
            kout[((size_t)bh * MKV + 64 + n) * 64 + d] = f2bf(v);
          else
            vout[((size_t)bh * MKV + 64 + n) * 64 + d] = f2bf(v);
        }
  } else if (EPI == 3) {
#pragma unroll
    for (int mi = 0; mi < 4; mi++)
#pragma unroll
      for (int ni = 0; ni < 4; ni++)
#pragma unroll
        for (int r = 0; r < 4; r++) {
          int c = ocol0 + ni * 16;
          size_t idx = (size_t)(orow0 + mi * 16 + r) * Ndim + c;
          outb[idx] = f2bf(resid[idx] + acc[mi][ni][r] + bias[c]);
        }
  } else if (EPI == 4) {
#pragma unroll
    for (int mi = 0; mi < 4; mi++)
#pragma unroll
      for (int ni = 0; ni < 4; ni++)
#pragma unroll
        for (int r = 0; r < 4; r++) {
          int c = ocol0 + ni * 16;
          size_t idx = (size_t)(orow0 + mi * 16 + r) * Ndim + c;
          outf[idx] = bf2f(residb[idx]) + acc[mi][ni][r] + bias[c];
        }
  } else {
#pragma unroll
    for (int mi = 0; mi < 4; mi++)
#pragma unroll
      for (int ni = 0; ni < 4; ni++)
#pragma unroll
        for (int r = 0; r < 4; r++) {
          int c = ocol0 + ni * 16;
          size_t idx = (size_t)(orow0 + mi * 16 + r) * Ndim + c;
          float z = acc[mi][ni][r] + bias[c];
          outb[idx] = f2bf(z / (1.f + __expf(-1.702f * z)));
        }
  }
}

// ---------------------------------------------------------------------------
// Flash attention v5 (R10-verified): 8-wave, exp2-domain softmax, defer-max,
// cvt_pk bf16 packing, LDS-staged K/V double-buffered, swapped QK^T.
__device__ __forceinline__ bf16x8 pexch(const unsigned pw[4][2], int kk,
                                        int src0, bool lo) {
  const unsigned a0 = pw[2 * kk][0], a1 = pw[2 * kk][1];
  const unsigned b0 = pw[2 * kk + 1][0], b1 = pw[2 * kk + 1][1];
  unsigned wA0 = (unsigned)__shfl((int)a0, src0);
  unsigned wA1 = (unsigned)__shfl((int)a1, src0);
  unsigned wB0 = (unsigned)__shfl((int)b0, src0);
  unsigned wB1 = (unsigned)__shfl((int)b1, src0);
  unsigned wA0h = (unsigned)__shfl((int)a0, src0 + 16);
  unsigned wA1h = (unsigned)__shfl((int)a1, src0 + 16);
  unsigned wB0h = (unsigned)__shfl((int)b0, src0 + 16);
  unsigned wB1h = (unsigned)__shfl((int)b1, src0 + 16);
  union { unsigned u[4]; bf16x8 v; } pf;
  pf.u[0] = lo ? wA0 : wB0;
  pf.u[1] = lo ? wA1 : wB1;
  pf.u[2] = lo ? wA0h : wB0h;
  pf.u[3] = lo ? wA1h : wB1h;
  return pf.v;
}

__global__ __launch_bounds__(512, 4) void flash_attn(
    const unsigned short* __restrict__ Qb, const unsigned short* __restrict__ Kb,
    const unsigned short* __restrict__ Vt, unsigned short* __restrict__ Ob) {
  __shared__ __align__(16) unsigned short KT[2][4096];
  __shared__ __align__(16) unsigned short VT[2][4096];
  const int t = threadIdx.x;
  const int w = t >> 6, l = t & 63;
  const int g = l >> 4, r15 = l & 15;
  const int bh = blockIdx.x, qt = blockIdx.y;
  const unsigned short* Kbh = Kb + (size_t)bh * MKV * 64;
  const unsigned short* Vbh = Vt + (size_t)bh * 64 * MKV;
  const int srow = t >> 3;
  const int scb = ((t & 7) << 4) ^ ((srow & 7) << 4);
  const char* Ksrc0 = (const char*)Kbh + srow * 128 + scb;
  const char* Vsrc0 = (const char*)Vbh + srow * (MKV * 2) + scb;
  const int qbase = qt * 256 + w * 32;
  const unsigned short* Qr0 = Qb + ((size_t)bh * 1024 + qbase + r15) * 64;
  const bf16x8 qf00 = *(const bf16x8*)(Qr0 + g * 8);
  const bf16x8 qf01 = *(const bf16x8*)(Qr0 + 32 + g * 8);
  const bf16x8 qf10 = *(const bf16x8*)(Qr0 + 16 * 64 + g * 8);
  const bf16x8 qf11 = *(const bf16x8*)(Qr0 + 16 * 64 + 32 + g * 8);
  f32x4 Oa0[4] = {}, Oa1[4] = {};
  float m0 = -1e30f, l0 = 0.f, m1 = -1e30f, l1 = 0.f;
  const int src0 = r15 + ((l & 16) << 1);
  const bool lo = (l < 32);
  const int rx = (r15 & 7) << 4;
  GLDS16(Ksrc0, &KT[0][t * 8]);
  GLDS16(Vsrc0, &VT[0][t * 8]);
  __syncthreads();
  int cur = 0;
  for (int kt = 0; kt < 17; ++kt) {
    if (kt < 16) {
      GLDS16(Ksrc0 + (kt + 1) * 8192, &KT[cur ^ 1][t * 8]);
      GLDS16(Vsrc0 + (kt + 1) * 128, &VT[cur ^ 1][t * 8]);
    }
    const char* Kl = (const char*)&KT[cur][0];
    const char* Vl = (const char*)&VT[cur][0];
    f32x4 S0[4], S1[4];
#pragma unroll
    for (int jc = 0; jc < 4; jc++) {
      const char* kr = Kl + jc * 2048 + r15 * 128;
      bf16x8 k0 = *(const bf16x8*)(kr + ((g * 16) ^ rx));
      bf16x8 k1 = *(const bf16x8*)(kr + ((64 + g * 16) ^ rx));
      f32x4 a0 = {}, a1 = {};
      a0 = __builtin_amdgcn_mfma_f32_16x16x32_bf16(k0, qf00, a0, 0, 0, 0);
      a0 = __builtin_amdgcn_mfma_f32_16x16x32_bf16(k1, qf01, a0, 0, 0, 0);
      a1 = __builtin_amdgcn_mfma_f32_16x16x32_bf16(k0, qf10, a1, 0, 0, 0);
      a1 = __builtin_amdgcn_mfma_f32_16x16x32_bf16(k1, qf11, a1, 0, 0, 0);
      S0[jc] = a0; S1[jc] = a1;
    }
    float mx0 = S0[0][0], mx1 = S1[0][0];
#pragma unroll
    for (int jc = 0; jc < 4; jc++)
#pragma unroll
      for (int r = 0; r < 4; r++) {
        mx0 = fmaxf(mx0, S0[jc][r]);
        mx1 = fmaxf(mx1, S1[jc][r]);
      }
    mx0 = fmaxf(mx0, __shfl_xor(mx0, 16));
    mx0 = fmaxf(mx0, __shfl_xor(mx0, 32));
    mx1 = fmaxf(mx1, __shfl_xor(mx1, 16));
    mx1 = fmaxf(mx1, __shfl_xor(mx1, 32));
    if (__any((mx0 > m0 + 8.f) || (mx1 > m1 + 8.f))) {
      float mn0 = fmaxf(m0, mx0);
      float sc0 = exp2f(m0 - mn0);
      m0 = mn0; l0 *= sc0;
      float mn1 = fmaxf(m1, mx1);
      float sc1 = exp2f(m1 - mn1);
      m1 = mn1; l1 *= sc1;
#pragma unroll
      for (int db = 0; db < 4; db++)
#pragma unroll
        for (int r = 0; r < 4; r++) {
          Oa0[db][r] *= sc0;
          Oa1[db][r] *= sc1;
        }
    }
    float rs0 = 0.f, rs1 = 0.f;
#pragma unroll
    for (int jc = 0; jc < 4; jc++)
#pragma unroll
      for (int r = 0; r < 4; r++) {
        float p0 = exp2f(S0[jc][r] - m0);
        float p1 = exp2f(S1[jc][r] - m1);
        S0[jc][r] = p0; S1[jc][r] = p1;
        rs0 += p0; rs1 += p1;
      }
    rs0 += __shfl_xor(rs0, 16);
    rs0 += __shfl_xor(rs0, 32);
    rs1 += __shfl_xor(rs1, 16);
    rs1 += __shfl_xor(rs1, 32);
    l0 += rs0; l1 += rs1;
    unsigned pw0[4][2], pw1[4][2];
#pragma unroll
    for (int jc = 0; jc < 4; jc++) {
      pw0[jc][0] = cvt_pk_bf16(S0[jc][0], S0[jc][1]);
      pw0[jc][1] = cvt_pk_bf16(S0[jc][2], S0[jc][3]);
      pw1[jc][0] = cvt_pk_bf16(S1[jc][0], S1[jc][1]);
      pw1[jc][1] = cvt_pk_bf16(S1[jc][2], S1[jc][3]);
    }
#pragma unroll
    for (int kk = 0; kk < 2; kk++) {
      bf16x8 pf0 = pexch(pw0, kk, src0, lo);
      bf16x8 pf1 = pexch(pw1, kk, src0, lo);
#pragma unroll
      for (int db = 0; db < 4; db++) {
        bf16x8 va = *(const bf16x8*)(Vl + db * 2048 + r15 * 128 +
                                     ((kk * 64 + g * 16) ^ rx));
        Oa0[db] = __builtin_amdgcn_mfma_f32_16x16x32_bf16(va, pf0, Oa0[db], 0, 0, 0);
        Oa1[db] = __builtin_amdgcn_mfma_f32_16x16x32_bf16(va, pf1, Oa1[db], 0, 0, 0);
      }
    }
    __syncthreads();
    cur ^= 1;
  }
  const int b = bh >> 4, h = bh & 15;
  const float i0 = 1.f / l0, i1 = 1.f / l1;
  const int n0 = qbase + r15;
#pragma unroll
  for (int db = 0; db < 4; db++) {
    u16x4 o;
#pragma unroll
    for (int r = 0; r < 4; r++) o[r] = f2bf(Oa0[db][r] * i0);
    *(u16x4*)(Ob + ((size_t)b * 1024 + n0) * 1024 + h * 64 + db * 16 + g * 4) = o;
#pragma unroll
    for (int r = 0; r < 4; r++) o[r] = f2bf(Oa1[db][r] * i1);
    *(u16x4*)(Ob + ((size_t)b * 1024 + n0 + 16) * 1024 + h * 64 + db * 16 + g * 4) = o;
  }
}

// ---------------------------------------------------------------------------
extern "C" void kernel_launch(void* const* d_in, const int* in_sizes, int n_in,
                              void* d_out, int out_size, void* d_ws, size_t ws_size,
                              hipStream_t stream) {
  const float* x       = (const float*)d_in[0];
  const float* pk      = (const float*)d_in[1];
  const float* pv      = (const float*)d_in[2];
  const float* qkv_w   = (const float*)d_in[3];
  const float* proj_w  = (const float*)d_in[4];
  const float* proj_b  = (const float*)d_in[5];
  const float* ln1_g   = (const float*)d_in[6];
  const float* ln1_b   = (const float*)d_in[7];
  const float* ln2_g   = (const float*)d_in[8];
  const float* ln2_b   = (const float*)d_in[9];
  const float* fc_w    = (const float*)d_in[10];
  const float* fc_b    = (const float*)d_in[11];
  const float* cproj_w = (const float*)d_in[12];
  const float* cproj_b = (const float*)d_in[13];
  float* out = (float*)d_out;
  char* ws = (char*)d_ws;

  unsigned short* qkv_wb   = (unsigned short*)(ws + 0);          // 6291456
  unsigned short* proj_wb  = (unsigned short*)(ws + 6291456);    // 2097152
  unsigned short* fc_wb    = (unsigned short*)(ws + 8388608);    // 8388608
  unsigned short* cproj_wb = (unsigned short*)(ws + 16777216);   // 8388608
  unsigned short* x1b      = (unsigned short*)(ws + 25165824);   // 16777216 (bf16 resid)
  unsigned short* h1       = (unsigned short*)(ws + 58720256);   // 16777216
  unsigned short* o_b      = h1;                                 // alias (h1 dead)
  unsigned short* h2       = (unsigned short*)(ws + 75497472);   // 16777216
  unsigned short* q_buf    = (unsigned short*)(ws + 92274688);   // 16777216
  unsigned short* Kb       = (unsigned short*)(ws + 109051904);  // 17825792
  unsigned short* Vb       = (unsigned short*)(ws + 126877696);  // 17825792
  unsigned short* Vt       = (unsigned short*)(ws + 144703488);  // 17825792
  unsigned short* h3       = (unsigned short*)(ws + 92274688);   // alias (dead)
  if (ws_size < 162529280u) return;

  // allow 64KB dynamic LDS (idempotent host-side calls — capture-safe)
  (void)hipFuncSetAttribute((const void*)gemm128<0>,
      hipFuncAttributeMaxDynamicSharedMemorySize, 65536);
  (void)hipFuncSetAttribute((const void*)gemm128<2>,
      hipFuncAttributeMaxDynamicSharedMemorySize, 65536);
  (void)hipFuncSetAttribute((const void*)gemm128<3>,
      hipFuncAttributeMaxDynamicSharedMemorySize, 65536);
  (void)hipFuncSetAttribute((const void*)gemm128<4>,
      hipFuncAttributeMaxDynamicSharedMemorySize, 65536);

  cast_all<<<6400 + ROWS, 256, 0, stream>>>(
      qkv_w, proj_w, fc_w, cproj_w, pk, pv,
      qkv_wb, proj_wb, fc_wb, cproj_wb, Kb, Vb, x, ln1_g, ln1_b, h1);
  gemm128<0><<<dim3(64, 24), 256, 65536, stream>>>(
      h1, qkv_wb, nullptr, nullptr, nullptr, nullptr, nullptr,
      q_buf, Kb, Vb, 3072, 1024);
  transpose_v<<<dim3(17, 128), 256, 0, stream>>>(Vb, Vt);
  flash_attn<<<dim3(128, 4), 512, 0, stream>>>(q_buf, Kb, Vt, o_b);
  gemm128<3><<<dim3(64, 8), 256, 65536, stream>>>(
      o_b, proj_wb, proj_b, x, nullptr, nullptr, x1b,
      nullptr, nullptr, nullptr, 1024, 1024);
  ln_bf16b<<<ROWS, 256, 0, stream>>>(x1b, ln2_g, ln2_b, h2);
  gemm128<2><<<dim3(64, 32), 256, 65536, stream>>>(
      h2, fc_wb, fc_b, nullptr, nullptr, nullptr, h3,
      nullptr, nullptr, nullptr, 4096, 1024);
  gemm128<4><<<dim3(64, 8), 256, 65536, stream>>>(
      h3, cproj_wb, cproj_b, nullptr, x1b, out, nullptr,
      nullptr, nullptr, nullptr, 1024, 4096);
}